// Round 1
// baseline (3140.343 us; speedup 1.0000x reference)
//
#include <hip/hip_runtime.h>
#include <math.h>

// EuclideanCodebook: x (8,4096,256) fp32, embed (8192,256) fp32
// out = embed[argmin_k ||x - e_k||^2]  (ref: argmax of -(x_sq - 2*dot + e_sq), first index wins ties)

#define DIM 256
#define KCODES 8192
#define NROWS 32768
#define BM 64          // rows per block
#define BN 128         // codes per k-tile
#define BC 64          // C-chunk
#define NKT (KCODES / BN)   // 64
#define NCC (DIM / BC)      // 4

__global__ __launch_bounds__(256, 3) void vq_argmin_gather(
    const float* __restrict__ x, const float* __restrict__ embed,
    float* __restrict__ out)
{
    // transposed tiles: xs[c][m], es[c][n]
    __shared__ __align__(16) float xs[BC * BM];   // 16 KB
    __shared__ __align__(16) float es[BC * BN];   // 32 KB

    const int tid = threadIdx.x;
    const int tx = tid & 15;    // code group: cols 4*tx..4*tx+3 and 64+4*tx..
    const int ty = tid >> 4;    // row group: rows 4*ty..4*ty+3
    const int row0 = blockIdx.x * BM;

    // ---- x_sq for this block's 64 rows (ref: sum(x*x, axis=1)) ----
    float xsq[4];
    {
        const int m = tid >> 2;        // 0..63
        const int quarter = tid & 3;   // 64 floats each
        const float* xr = x + (size_t)(row0 + m) * DIM + quarter * 64;
        float s = 0.f;
        for (int c = 0; c < 64; ++c) s = fmaf(xr[c], xr[c], s);
        es[tid] = s;                   // scratch
        __syncthreads();
        #pragma unroll
        for (int i = 0; i < 4; ++i) {
            const int r = 4 * ty + i;
            xsq[i] = ((es[4*r] + es[4*r+1]) + es[4*r+2]) + es[4*r+3];
        }
        __syncthreads();
    }

    float bd[4] = {INFINITY, INFINITY, INFINITY, INFINITY};
    int   bk[4] = {0, 0, 0, 0};

    for (int kt = 0; kt < NKT; ++kt) {
        const int k0 = kt * BN;
        float acc[4][8];
        #pragma unroll
        for (int i = 0; i < 4; ++i)
            #pragma unroll
            for (int j = 0; j < 8; ++j) acc[i][j] = 0.f;
        float e_acc = 0.f;   // e_sq partial (threads 0..127, code = tid)

        for (int cc = 0; cc < NCC; ++cc) {
            __syncthreads();
            {
                const int q = tid & 15;       // float4 column within chunk
                const int nbase = tid >> 4;   // +16 per pass
                // x chunk: 64 rows x 64 c
                #pragma unroll
                for (int p = 0; p < 4; ++p) {
                    const int m = nbase + 16 * p;
                    const float4 v = *(const float4*)(x + (size_t)(row0 + m) * DIM + cc * BC + 4 * q);
                    xs[(4*q + 0) * BM + m] = v.x;
                    xs[(4*q + 1) * BM + m] = v.y;
                    xs[(4*q + 2) * BM + m] = v.z;
                    xs[(4*q + 3) * BM + m] = v.w;
                }
                // e chunk: 128 codes x 64 c
                #pragma unroll
                for (int p = 0; p < 8; ++p) {
                    const int n = nbase + 16 * p;
                    const float4 v = *(const float4*)(embed + (size_t)(k0 + n) * DIM + cc * BC + 4 * q);
                    es[(4*q + 0) * BN + n] = v.x;
                    es[(4*q + 1) * BN + n] = v.y;
                    es[(4*q + 2) * BN + n] = v.z;
                    es[(4*q + 3) * BN + n] = v.w;
                }
            }
            __syncthreads();

            // e_sq partials (sequential over global c, ascending)
            if (tid < BN) {
                #pragma unroll 8
                for (int c = 0; c < BC; ++c) {
                    const float v = es[c * BN + tid];
                    e_acc = fmaf(v, v, e_acc);
                }
            }

            // microkernel: 4x8 per thread
            #pragma unroll 8
            for (int c = 0; c < BC; ++c) {
                const float4 a0 = *(const float4*)&xs[c * BM + 4 * ty];
                const float4 b0 = *(const float4*)&es[c * BN + 4 * tx];
                const float4 b1 = *(const float4*)&es[c * BN + 64 + 4 * tx];
                const float a[4] = {a0.x, a0.y, a0.z, a0.w};
                const float b[8] = {b0.x, b0.y, b0.z, b0.w, b1.x, b1.y, b1.z, b1.w};
                #pragma unroll
                for (int i = 0; i < 4; ++i)
                    #pragma unroll
                    for (int j = 0; j < 8; ++j)
                        acc[i][j] = fmaf(a[i], b[j], acc[i][j]);
            }
        }

        // ---- epilogue: broadcast e_sq through LDS, then argmin update ----
        __syncthreads();                 // all frag reads of es done
        if (tid < BN) es[tid] = e_acc;   // es[0][n] = e_sq of code k0+n
        __syncthreads();
        float esq[8];
        #pragma unroll
        for (int j = 0; j < 4; ++j) {
            esq[j]     = es[4*tx + j];
            esq[4 + j] = es[64 + 4*tx + j];
        }
        #pragma unroll
        for (int i = 0; i < 4; ++i) {
            #pragma unroll
            for (int j = 0; j < 8; ++j) {
                // ref rounding sequence: (x_sq - 2*dot) + e_sq ; 2*dot exact -> fmaf == np
                const float d = fmaf(-2.0f, acc[i][j], xsq[i]) + esq[j];
                const int kk = k0 + ((j < 4) ? (4*tx + j) : (64 + 4*tx + (j - 4)));
                if (d < bd[i]) { bd[i] = d; bk[i] = kk; }   // strict < : first index wins
            }
        }
    }

    // ---- per-row reduction across the 16 tx threads ----
    __syncthreads();
    float* red_d = xs;         // [BM][16]
    int*   red_k = (int*)es;   // [BM][16]
    #pragma unroll
    for (int i = 0; i < 4; ++i) {
        const int r = 4 * ty + i;
        red_d[r * 16 + tx] = bd[i];
        red_k[r * 16 + tx] = bk[i];
    }
    __syncthreads();
    int winner = 0;
    if (tid < BM) {
        float best = red_d[tid * 16];
        int   bidx = red_k[tid * 16];
        #pragma unroll
        for (int t = 1; t < 16; ++t) {
            const float d2 = red_d[tid * 16 + t];
            const int   k2 = red_k[tid * 16 + t];
            if (d2 < best || (d2 == best && k2 < bidx)) { best = d2; bidx = k2; }
        }
        winner = bidx;
    }
    __syncthreads();
    int* win = (int*)xs;
    if (tid < BM) win[tid] = winner;
    __syncthreads();

    // ---- gather: out[row] = embed[win[row]], coalesced float4 ----
    {
        const int q = tid & 63;
        const int rbase = tid >> 6;
        const float4* e4 = (const float4*)embed;
        float4* o4 = (float4*)out;
        #pragma unroll
        for (int p = 0; p < 16; ++p) {
            const int r = rbase + 4 * p;
            const int k = win[r];
            o4[(size_t)(row0 + r) * (DIM/4) + q] = e4[(size_t)k * (DIM/4) + q];
        }
    }
}

extern "C" void kernel_launch(void* const* d_in, const int* in_sizes, int n_in,
                              void* d_out, int out_size, void* d_ws, size_t ws_size,
                              hipStream_t stream) {
    const float* x = (const float*)d_in[0];
    const float* embed = (const float*)d_in[1];
    float* out = (float*)d_out;
    dim3 grid(NROWS / BM);   // 512 blocks
    dim3 block(256);
    hipLaunchKernelGGL(vq_argmin_gather, grid, block, 0, stream, x, embed, out);
}

// Round 2
// 546.147 us; speedup vs baseline: 5.7500x; 5.7500x over previous
//
#include <hip/hip_runtime.h>
#include <math.h>

// EuclideanCodebook: x (8,4096,256) fp32, embed (8192,256) fp32
// out = embed[argmin_k ||x - e_k||^2], first-index tie rule.
//
// Strategy:
//  K1/K2: split x,embed into bf16 hi/lo planes in ws (x = xh + xl exact-ish, 16+ bits)
//  K3:    e_sq per code (approx use only)
//  A:     MFMA phase: score[n] = dot(x,e_n) - 0.5*e_sq[n] via 3 bf16 products
//         (hh, hl, lh; ll dropped, err ~1e-4 << top-2 gap ~4). Per-lane top-2
//         per row-stream, merged to top-2 per (row, N-half) -> candidate indices.
//  B:     exact fp32 recheck of 4 candidates, bit-replicating the round-1
//         arithmetic (which passed absmax 0), then coalesced gather.

#define DIM 256
#define KCODES 8192
#define NROWS 32768

typedef unsigned short ushort_t;
typedef short s16x8 __attribute__((ext_vector_type(8)));
typedef float f32x4 __attribute__((ext_vector_type(4)));

// ---- ws layout (bytes) ----
#define XS_OFF 0u                      // 32768*512 bf16 = 33554432
#define ES_OFF 33554432u               // 8192*512 bf16  = 8388608
#define ESQ_OFF 41943040u              // 8192 f32       = 32768
#define KC_OFF 41975808u               // 32768*4 i32    = 524288
#define WS_NEED 42500096u

__device__ inline ushort_t f32_to_bf16_rne(float f) {
    unsigned u = __float_as_uint(f);
    unsigned r = (u + 0x7FFFu + ((u >> 16) & 1u)) >> 16;
    return (ushort_t)r;
}
__device__ inline float bf16_to_f32(ushort_t h) {
    return __uint_as_float(((unsigned)h) << 16);
}

// ---------------- K1/K2: split fp32 -> bf16 hi/lo planes ----------------
// dst layout per row: [hi(256) | lo(256)] bf16
__global__ void split_bf16(const float* __restrict__ src, ushort_t* __restrict__ dst, int n4) {
    int gid = blockIdx.x * 256 + threadIdx.x;
    if (gid >= n4) return;
    int row = gid >> 6;          // 64 float4 per row
    int cq = gid & 63;
    float4 v = ((const float4*)src)[gid];
    float vv[4] = {v.x, v.y, v.z, v.w};
    ushort_t h[4], l[4];
#pragma unroll
    for (int i = 0; i < 4; ++i) {
        h[i] = f32_to_bf16_rne(vv[i]);
        l[i] = f32_to_bf16_rne(vv[i] - bf16_to_f32(h[i]));
    }
    ushort_t* base = dst + (size_t)row * 512 + cq * 4;
    *(ushort4*)(base)       = make_ushort4(h[0], h[1], h[2], h[3]);
    *(ushort4*)(base + 256) = make_ushort4(l[0], l[1], l[2], l[3]);
}

// ---------------- K3: e_sq (approx use only) ----------------
__global__ void compute_esq(const float* __restrict__ embed, float* __restrict__ esq) {
    int r = blockIdx.x * 256 + threadIdx.x;
    if (r >= KCODES) return;
    const float4* e4 = (const float4*)(embed + (size_t)r * DIM);
    float s = 0.f;
    for (int i = 0; i < 64; ++i) {
        float4 v = e4[i];
        s = fmaf(v.x, v.x, s); s = fmaf(v.y, v.y, s);
        s = fmaf(v.z, v.z, s); s = fmaf(v.w, v.w, s);
    }
    esq[r] = s;
}

// ---------------- Phase A: MFMA scoring + top-2 candidates ----------------
// grid (256 M-blocks, 2 N-halves), 256 threads (4 waves).
// Block: 128 rows x 4096 codes (one half), N-tiles of 128 codes, C-chunks of 64.
// Wave w: rows (w&1)*64, cols (w>>1)*64 of the 128x128 tile; 4x4 grid of 16x16 mfma.
#define GLOAD_LDS16(gp, lp) \
    __builtin_amdgcn_global_load_lds((const __attribute__((address_space(1))) void*)(gp), \
                                     (__attribute__((address_space(3))) void*)(lp), 16, 0, 0)

__global__ __launch_bounds__(256, 2) void vq_phaseA(
    const ushort_t* __restrict__ Xs, const ushort_t* __restrict__ Es,
    const float* __restrict__ esq, int* __restrict__ kcand)
{
    // planes: A-h [0], A-l [8192], B-h [16384], B-l [24576] (ushort units), 64KB total
    __shared__ __align__(16) ushort_t smem[4 * 128 * 64];

    const int tid = threadIdx.x;
    const int lane = tid & 63;
    const int wv = tid >> 6;
    const int lm = lane & 15;
    const int quad = lane >> 4;
    const int arow = (wv & 1) * 64;   // row offset of this wave's 64x64 tile
    const int coff = (wv >> 1) * 64;  // col offset
    const int rowblk = blockIdx.x * 128;
    const int half = blockIdx.y;
    const int nbase = half * 4096;

    // staging roles: wave0->A-h, wave1->A-l, wave2->B-h, wave3->B-l (16KB each)
    const ushort_t* gsrc = (wv < 2) ? Xs : Es;
    const int plane = wv & 1;
    const int lr = lane >> 3;               // row within 8-row slice
    const int gblk = (lane & 7) ^ lr;       // XOR-swizzled 16B-block (global side)

    // per-lane top-2 per row-slot (16 slots: am*4 + r)
    float s1[16], s2[16];
    int k1[16], k2[16];
#pragma unroll
    for (int i = 0; i < 16; ++i) { s1[i] = -INFINITY; s2[i] = -INFINITY; k1[i] = 0x7fffffff; k2[i] = 0x7fffffff; }

    for (int nt = 0; nt < 32; ++nt) {
        const int n0 = nbase + nt * 128;

        // acc init: -0.5*e_sq[col] (all 4 regs of a tile share the column)
        f32x4 acc[4][4];
#pragma unroll
        for (int bn = 0; bn < 4; ++bn) {
            float ev = -0.5f * esq[n0 + coff + bn * 16 + lm];
            f32x4 ini = {ev, ev, ev, ev};
#pragma unroll
            for (int am = 0; am < 4; ++am) acc[am][bn] = ini;
        }

        const size_t growbase = (wv < 2) ? (size_t)rowblk : (size_t)(n0);

        for (int cc = 0; cc < 4; ++cc) {
            __syncthreads();   // previous compute done reading LDS
            // stage 16KB per wave: 16 x (1KB = 8 rows x 64 bf16)
#pragma unroll
            for (int i = 0; i < 16; ++i) {
                const ushort_t* g = gsrc +
                    ((growbase + (size_t)(i * 8 + lr)) * 512 + plane * 256 + cc * 64 + gblk * 8);
                ushort_t* l = smem + wv * 8192 + i * 512;
                GLOAD_LDS16(g, l);
            }
            __syncthreads();   // drains vmcnt, staging visible

            // compute: 2 K-steps of 32, combos hh/hl/lh
#pragma unroll
            for (int ks = 0; ks < 2; ++ks) {
                const int kswz = (((ks * 4 + quad) ^ (lm & 7)) * 8);
                s16x8 ah[4], al[4], bh[4], bl[4];
#pragma unroll
                for (int am = 0; am < 4; ++am) {
                    const int r = arow + am * 16 + lm;
                    ah[am] = *(const s16x8*)(smem + r * 64 + kswz);
                    al[am] = *(const s16x8*)(smem + 8192 + r * 64 + kswz);
                }
#pragma unroll
                for (int bn = 0; bn < 4; ++bn) {
                    const int r = coff + bn * 16 + lm;
                    bh[bn] = *(const s16x8*)(smem + 16384 + r * 64 + kswz);
                    bl[bn] = *(const s16x8*)(smem + 24576 + r * 64 + kswz);
                }
#pragma unroll
                for (int am = 0; am < 4; ++am)
#pragma unroll
                    for (int bn = 0; bn < 4; ++bn)
                        acc[am][bn] = __builtin_amdgcn_mfma_f32_16x16x32_bf16(ah[am], bh[bn], acc[am][bn], 0, 0, 0);
#pragma unroll
                for (int am = 0; am < 4; ++am)
#pragma unroll
                    for (int bn = 0; bn < 4; ++bn)
                        acc[am][bn] = __builtin_amdgcn_mfma_f32_16x16x32_bf16(ah[am], bl[bn], acc[am][bn], 0, 0, 0);
#pragma unroll
                for (int am = 0; am < 4; ++am)
#pragma unroll
                    for (int bn = 0; bn < 4; ++bn)
                        acc[am][bn] = __builtin_amdgcn_mfma_f32_16x16x32_bf16(al[am], bh[bn], acc[am][bn], 0, 0, 0);
            }
        }

        // epilogue: top-2 update (registers only)
#pragma unroll
        for (int bn = 0; bn < 4; ++bn) {
            const int kk = n0 + coff + bn * 16 + lm;
#pragma unroll
            for (int am = 0; am < 4; ++am)
#pragma unroll
                for (int r = 0; r < 4; ++r) {
                    const float v = acc[am][bn][r];
                    const int slot = am * 4 + r;
                    const bool c1 = v > s1[slot];
                    const bool c2 = v > s2[slot];
                    float ns2 = c2 ? v : s2[slot];
                    int nk2 = c2 ? kk : k2[slot];
                    s2[slot] = c1 ? s1[slot] : ns2;
                    k2[slot] = c1 ? k1[slot] : nk2;
                    s1[slot] = c1 ? v : s1[slot];
                    k1[slot] = c1 ? kk : k1[slot];
                }
        }
    }

    // ---- merge: 32 streams x top2 = 64 pairs per row -> top2 per row ----
    __syncthreads();
    float* sb = (float*)smem;                  // [128][64] scores (32KB)
    int* kb = (int*)(smem + 2 * 128 * 64);     // [128][64] indices (32KB)
#pragma unroll
    for (int slot = 0; slot < 16; ++slot) {
        const int row = arow + (slot >> 2) * 16 + quad * 4 + (slot & 3);
        const int pos = (wv >> 1) * 32 + lm * 2;
        sb[row * 64 + pos] = s1[slot];  kb[row * 64 + pos] = k1[slot];
        sb[row * 64 + pos + 1] = s2[slot];  kb[row * 64 + pos + 1] = k2[slot];
    }
    __syncthreads();
    if (tid < 128) {
        float b1 = -INFINITY, b2 = -INFINITY;
        int i1 = 0x7fffffff, i2 = 0x7fffffff;
        for (int p = 0; p < 64; ++p) {
            const float s = sb[tid * 64 + p];
            const int k = kb[tid * 64 + p];
            if (s > b1 || (s == b1 && k < i1)) { b2 = b1; i2 = i1; b1 = s; i1 = k; }
            else if (s > b2 || (s == b2 && k < i2)) { b2 = s; i2 = k; }
        }
        const int rg = rowblk + tid;
        kcand[rg * 4 + half * 2] = i1;
        kcand[rg * 4 + half * 2 + 1] = i2;
    }
}

// ---------------- Phase B: exact fp32 recheck (round-1 arithmetic) + gather ----------------
__global__ __launch_bounds__(256) void vq_phaseB(
    const float* __restrict__ x, const float* __restrict__ embed,
    const int* __restrict__ kcand, float* __restrict__ out)
{
    __shared__ int win[256];
    const int tid = threadIdx.x;
    const int row0 = blockIdx.x * 256;
    const int r = row0 + tid;

    int4 kc = ((const int4*)kcand)[r];
    int ks[4] = {kc.x, kc.y, kc.z, kc.w};
    // sort ascending (first-index tie rule needs ascending evaluation + strict <)
#define CSWAP(a, b) { if (ks[a] > ks[b]) { int t = ks[a]; ks[a] = ks[b]; ks[b] = t; } }
    CSWAP(0, 1) CSWAP(2, 3) CSWAP(0, 2) CSWAP(1, 3) CSWAP(1, 2)
#undef CSWAP

    const float4* x4 = (const float4*)(x + (size_t)r * DIM);
    // x_sq: 4 chunks of 64 sequential fmaf, ((s0+s1)+s2)+s3 — replicates round 1
    float cs[4];
#pragma unroll
    for (int co = 0; co < 4; ++co) {
        float s = 0.f;
        for (int c4 = 0; c4 < 16; ++c4) {
            float4 v = x4[co * 16 + c4];
            s = fmaf(v.x, v.x, s); s = fmaf(v.y, v.y, s);
            s = fmaf(v.z, v.z, s); s = fmaf(v.w, v.w, s);
        }
        cs[co] = s;
    }
    const float xsq = ((cs[0] + cs[1]) + cs[2]) + cs[3];

    float bd = INFINITY;
    int bk = 0;
#pragma unroll
    for (int i = 0; i < 4; ++i) {
        const int k = ks[i];
        const float4* e4 = (const float4*)(embed + (size_t)k * DIM);
        float dot = 0.f, es = 0.f;
        for (int c4 = 0; c4 < 64; ++c4) {
            float4 xv = x4[c4], ev = e4[c4];
            dot = fmaf(xv.x, ev.x, dot); dot = fmaf(xv.y, ev.y, dot);
            dot = fmaf(xv.z, ev.z, dot); dot = fmaf(xv.w, ev.w, dot);
            es = fmaf(ev.x, ev.x, es); es = fmaf(ev.y, ev.y, es);
            es = fmaf(ev.z, ev.z, es); es = fmaf(ev.w, ev.w, es);
        }
        const float d = fmaf(-2.0f, dot, xsq) + es;   // round-1 rounding sequence
        if (d < bd) { bd = d; bk = k; }               // ascending k + strict <
    }
    win[tid] = bk;
    __syncthreads();

    // coalesced gather: out[row] = embed[win[row]]
    const float4* e4 = (const float4*)embed;
    float4* o4 = (float4*)out;
    for (int p = 0; p < 64; ++p) {
        const int rl = (tid >> 6) + (p << 2);
        const int k = win[rl];
        o4[(size_t)(row0 + rl) * 64 + (tid & 63)] = e4[(size_t)k * 64 + (tid & 63)];
    }
}

// ---------------- Fallback (round-1 kernel, passed absmax 0) ----------------
#define BM 64
#define BN 128
#define BC 64
#define NKT (KCODES / BN)
#define NCC (DIM / BC)

__global__ __launch_bounds__(256, 3) void vq_argmin_gather(
    const float* __restrict__ x, const float* __restrict__ embed,
    float* __restrict__ out)
{
    __shared__ __align__(16) float xs[BC * BM];
    __shared__ __align__(16) float es[BC * BN];
    const int tid = threadIdx.x;
    const int tx = tid & 15;
    const int ty = tid >> 4;
    const int row0 = blockIdx.x * BM;
    float xsq[4];
    {
        const int m = tid >> 2;
        const int quarter = tid & 3;
        const float* xr = x + (size_t)(row0 + m) * DIM + quarter * 64;
        float s = 0.f;
        for (int c = 0; c < 64; ++c) s = fmaf(xr[c], xr[c], s);
        es[tid] = s;
        __syncthreads();
#pragma unroll
        for (int i = 0; i < 4; ++i) {
            const int r = 4 * ty + i;
            xsq[i] = ((es[4*r] + es[4*r+1]) + es[4*r+2]) + es[4*r+3];
        }
        __syncthreads();
    }
    float bd[4] = {INFINITY, INFINITY, INFINITY, INFINITY};
    int bk[4] = {0, 0, 0, 0};
    for (int kt = 0; kt < NKT; ++kt) {
        const int k0 = kt * BN;
        float acc[4][8];
#pragma unroll
        for (int i = 0; i < 4; ++i)
#pragma unroll
            for (int j = 0; j < 8; ++j) acc[i][j] = 0.f;
        float e_acc = 0.f;
        for (int cc = 0; cc < NCC; ++cc) {
            __syncthreads();
            {
                const int q = tid & 15;
                const int nb = tid >> 4;
#pragma unroll
                for (int p = 0; p < 4; ++p) {
                    const int m = nb + 16 * p;
                    const float4 v = *(const float4*)(x + (size_t)(row0 + m) * DIM + cc * BC + 4 * q);
                    xs[(4*q+0)*BM+m] = v.x; xs[(4*q+1)*BM+m] = v.y;
                    xs[(4*q+2)*BM+m] = v.z; xs[(4*q+3)*BM+m] = v.w;
                }
#pragma unroll
                for (int p = 0; p < 8; ++p) {
                    const int n = nb + 16 * p;
                    const float4 v = *(const float4*)(embed + (size_t)(k0 + n) * DIM + cc * BC + 4 * q);
                    es[(4*q+0)*BN+n] = v.x; es[(4*q+1)*BN+n] = v.y;
                    es[(4*q+2)*BN+n] = v.z; es[(4*q+3)*BN+n] = v.w;
                }
            }
            __syncthreads();
            if (tid < BN) {
#pragma unroll 8
                for (int c = 0; c < BC; ++c) { const float v = es[c*BN+tid]; e_acc = fmaf(v, v, e_acc); }
            }
#pragma unroll 8
            for (int c = 0; c < BC; ++c) {
                const float4 a0 = *(const float4*)&xs[c*BM+4*ty];
                const float4 b0 = *(const float4*)&es[c*BN+4*tx];
                const float4 b1 = *(const float4*)&es[c*BN+64+4*tx];
                const float a[4] = {a0.x, a0.y, a0.z, a0.w};
                const float b[8] = {b0.x, b0.y, b0.z, b0.w, b1.x, b1.y, b1.z, b1.w};
#pragma unroll
                for (int i = 0; i < 4; ++i)
#pragma unroll
                    for (int j = 0; j < 8; ++j) acc[i][j] = fmaf(a[i], b[j], acc[i][j]);
            }
        }
        __syncthreads();
        if (tid < BN) es[tid] = e_acc;
        __syncthreads();
        float esq[8];
#pragma unroll
        for (int j = 0; j < 4; ++j) { esq[j] = es[4*tx+j]; esq[4+j] = es[64+4*tx+j]; }
#pragma unroll
        for (int i = 0; i < 4; ++i)
#pragma unroll
            for (int j = 0; j < 8; ++j) {
                const float d = fmaf(-2.0f, acc[i][j], xsq[i]) + esq[j];
                const int kk = k0 + ((j < 4) ? (4*tx+j) : (64+4*tx+(j-4)));
                if (d < bd[i]) { bd[i] = d; bk[i] = kk; }
            }
    }
    __syncthreads();
    float* red_d = xs;
    int* red_k = (int*)es;
#pragma unroll
    for (int i = 0; i < 4; ++i) { const int r = 4*ty+i; red_d[r*16+tx] = bd[i]; red_k[r*16+tx] = bk[i]; }
    __syncthreads();
    int winner = 0;
    if (tid < BM) {
        float best = red_d[tid*16]; int bidx = red_k[tid*16];
#pragma unroll
        for (int t = 1; t < 16; ++t) {
            const float d2 = red_d[tid*16+t]; const int k2 = red_k[tid*16+t];
            if (d2 < best || (d2 == best && k2 < bidx)) { best = d2; bidx = k2; }
        }
        winner = bidx;
    }
    __syncthreads();
    int* wn = (int*)xs;
    if (tid < BM) wn[tid] = winner;
    __syncthreads();
    {
        const int q = tid & 63;
        const int rb = tid >> 6;
        const float4* e4 = (const float4*)embed;
        float4* o4 = (float4*)out;
#pragma unroll
        for (int p = 0; p < 16; ++p) {
            const int rr = rb + 4 * p;
            const int k = wn[rr];
            o4[(size_t)(row0 + rr) * 64 + q] = e4[(size_t)k * 64 + q];
        }
    }
}

extern "C" void kernel_launch(void* const* d_in, const int* in_sizes, int n_in,
                              void* d_out, int out_size, void* d_ws, size_t ws_size,
                              hipStream_t stream) {
    const float* x = (const float*)d_in[0];
    const float* embed = (const float*)d_in[1];
    float* out = (float*)d_out;

    if (ws_size < (size_t)WS_NEED) {
        hipLaunchKernelGGL(vq_argmin_gather, dim3(NROWS / BM), dim3(256), 0, stream, x, embed, out);
        return;
    }
    char* ws = (char*)d_ws;
    ushort_t* Xs = (ushort_t*)(ws + XS_OFF);
    ushort_t* Es = (ushort_t*)(ws + ES_OFF);
    float* esq = (float*)(ws + ESQ_OFF);
    int* kcand = (int*)(ws + KC_OFF);

    hipLaunchKernelGGL(split_bf16, dim3(8192), dim3(256), 0, stream, x, Xs, 2097152);
    hipLaunchKernelGGL(split_bf16, dim3(2048), dim3(256), 0, stream, embed, Es, 524288);
    hipLaunchKernelGGL(compute_esq, dim3(32), dim3(256), 0, stream, embed, esq);
    hipLaunchKernelGGL(vq_phaseA, dim3(256, 2), dim3(256), 0, stream, Xs, Es, esq, kcand);
    hipLaunchKernelGGL(vq_phaseB, dim3(128), dim3(256), 0, stream, x, embed, kcand, out);
}

// Round 3
// 346.018 us; speedup vs baseline: 9.0756x; 1.5784x over previous
//
#include <hip/hip_runtime.h>
#include <math.h>

// EuclideanCodebook: x (8,4096,256) fp32, embed (8192,256) fp32
// out = embed[argmin_k ||x - e_k||^2], first-index tie rule.
//
// R3 strategy: single fp16 MFMA product for approximate scores
//   score[n] = dot_f16(x, e_n) - 0.5*e_sq[n]   (err std ~0.006 << top-2 gap ~6.8)
// A-fragments register-resident (full K), B staged full-K per n-tile via
// swizzled global_load_lds. Packed (score|index) top-2 per 64-code stream,
// merged top-4 per half -> 8 candidates/row -> exact fp32 recheck (round-1/2
// validated arithmetic) -> gather.

#define DIM 256
#define KCODES 8192
#define NROWS 32768

typedef _Float16 half8 __attribute__((ext_vector_type(8)));
typedef _Float16 half4_t __attribute__((ext_vector_type(4)));
typedef float f32x4 __attribute__((ext_vector_type(4)));

// ---- ws layout (bytes) ----
#define ES_OFF 0u                     // 8192*256 f16 = 4194304
#define ESQ_OFF 4194304u              // 8192 f32     = 32768
#define KC_OFF 4227072u               // 32768*8 i32  = 1048576
#define WS_NEED 5275648u

#define GLOAD_LDS16(gp, lp) \
    __builtin_amdgcn_global_load_lds((const __attribute__((address_space(1))) void*)(gp), \
                                     (__attribute__((address_space(3))) void*)(lp), 16, 0, 0)

// ---------------- convert embed fp32 -> fp16 ----------------
__global__ void cvt_f16(const float* __restrict__ src, _Float16* __restrict__ dst, int n4) {
    int gid = blockIdx.x * 256 + threadIdx.x;
    if (gid >= n4) return;
    float4 v = ((const float4*)src)[gid];
    half4_t h;
    h[0] = (_Float16)v.x; h[1] = (_Float16)v.y; h[2] = (_Float16)v.z; h[3] = (_Float16)v.w;
    ((half4_t*)dst)[gid] = h;
}

// ---------------- e_sq (used in approximate scores only) ----------------
__global__ void compute_esq(const float* __restrict__ embed, float* __restrict__ esq) {
    int r = blockIdx.x * 256 + threadIdx.x;
    if (r >= KCODES) return;
    const float4* e4 = (const float4*)(embed + (size_t)r * DIM);
    float s = 0.f;
    for (int i = 0; i < 64; ++i) {
        float4 v = e4[i];
        s = fmaf(v.x, v.x, s); s = fmaf(v.y, v.y, s);
        s = fmaf(v.z, v.z, s); s = fmaf(v.w, v.w, s);
    }
    esq[r] = s;
}

// ---------------- Phase A: fp16 MFMA scoring + packed top-2 ----------------
// grid (512 row-blocks, 2 halves), 256 threads (4 waves, all sharing 64 rows,
// cols split 4 ways: wave wv covers cols wv*32 .. wv*32+31 of each 128-tile).
__global__ __launch_bounds__(256, 2) void vq_phaseA_f16(
    const float* __restrict__ x, const _Float16* __restrict__ Es,
    const float* __restrict__ esq, int* __restrict__ kcand)
{
    __shared__ __align__(16) _Float16 Bs[128 * 256];   // 64 KB

    const int tid = threadIdx.x;
    const int lane = tid & 63;
    const int wv = tid >> 6;
    const int lm = lane & 15;
    const int quad = lane >> 4;
    const int coff = wv * 32;
    const int rowblk = blockIdx.x * 64;
    const int nhalf = blockIdx.y;
    const int nbase = nhalf * 4096;

    // A fragments register-resident: af[am][ks] = x[rowblk+am*16+lm][ks*32+quad*8 ..+8]
    half8 af[4][8];
#pragma unroll
    for (int am = 0; am < 4; ++am) {
        const float* xr = x + (size_t)(rowblk + am * 16 + lm) * DIM + quad * 8;
#pragma unroll
        for (int ks = 0; ks < 8; ++ks) {
            const float4 a = *(const float4*)(xr + ks * 32);
            const float4 b = *(const float4*)(xr + ks * 32 + 4);
            half8 h;
            h[0] = (_Float16)a.x; h[1] = (_Float16)a.y; h[2] = (_Float16)a.z; h[3] = (_Float16)a.w;
            h[4] = (_Float16)b.x; h[5] = (_Float16)b.y; h[6] = (_Float16)b.z; h[7] = (_Float16)b.w;
            af[am][ks] = h;
        }
    }

    // packed (score | 8191-safe index in low 13 mantissa bits) top-2 per row-slot.
    // All scores are negative (min |e|^2 ~ 170 > 2*max dot ~ 156), so float-max
    // on packed values orders by score and tie-breaks toward SMALLER index.
    float p1[16], p2[16];
#pragma unroll
    for (int i = 0; i < 16; ++i) { p1[i] = -INFINITY; p2[i] = -INFINITY; }

    int kv[2] = { nbase + coff + lm, nbase + coff + 16 + lm };

    for (int nt = 0; nt < 32; ++nt) {
        const int n0 = nbase + nt * 128;
        __syncthreads();   // previous tile's reads complete
        // stage B tile: 128 codes x 256 f16; wave stages codes [wv*32, wv*32+32).
        // 16B-block column XOR-swizzled with (code&7) on the GLOBAL side;
        // LDS side is lane-contiguous (base + lane*16) as required.
#pragma unroll
        for (int i = 0; i < 16; ++i) {
            const int clb = wv * 32 + 2 * i;
            const int cl = clb + (lane >> 5);
            const int blk = (lane & 31) ^ (cl & 7);
            const _Float16* g = Es + (size_t)(n0 + cl) * 256 + blk * 8;
            GLOAD_LDS16(g, Bs + clb * 256);
        }
        __syncthreads();   // staging visible

        f32x4 acc[4][2];
        {
            const float e0 = -0.5f * esq[n0 + coff + lm];
            const float e1 = -0.5f * esq[n0 + coff + 16 + lm];
            const f32x4 i0 = {e0, e0, e0, e0};
            const f32x4 i1 = {e1, e1, e1, e1};
#pragma unroll
            for (int am = 0; am < 4; ++am) { acc[am][0] = i0; acc[am][1] = i1; }
        }
#pragma unroll
        for (int ks = 0; ks < 8; ++ks) {
            half8 bh[2];
#pragma unroll
            for (int bn = 0; bn < 2; ++bn) {
                const int cl = coff + bn * 16 + lm;
                bh[bn] = *(const half8*)(Bs + cl * 256 + (((ks * 4 + quad) ^ (lm & 7)) * 8));
            }
#pragma unroll
            for (int am = 0; am < 4; ++am)
#pragma unroll
                for (int bn = 0; bn < 2; ++bn)
                    acc[am][bn] = __builtin_amdgcn_mfma_f32_16x16x32_f16(af[am][ks], bh[bn], acc[am][bn], 0, 0, 0);
        }

        // epilogue: pack + branchless top-2 (3 VALU ops/value: and_or, max/min, max)
#pragma unroll
        for (int bn = 0; bn < 2; ++bn) {
            const unsigned kkb = (unsigned)kv[bn];
#pragma unroll
            for (int am = 0; am < 4; ++am)
#pragma unroll
                for (int r = 0; r < 4; ++r) {
                    const float pv = __uint_as_float((__float_as_uint(acc[am][bn][r]) & 0xFFFFE000u) | kkb);
                    const int slot = am * 4 + r;
                    p2[slot] = fmaxf(p2[slot], fminf(p1[slot], pv));
                    p1[slot] = fmaxf(p1[slot], pv);
                }
        }
        kv[0] += 128; kv[1] += 128;
    }

    // merge: per row, 64 streams x top2 = 128 packed values -> top-4 per half
    __syncthreads();
    float* sb = (float*)Bs;    // [64][128], 32 KB
#pragma unroll
    for (int slot = 0; slot < 16; ++slot) {
        const int row = (slot >> 2) * 16 + quad * 4 + (slot & 3);   // MFMA C-layout row
        const int pos = wv * 32 + lm * 2;
        sb[row * 128 + pos] = p1[slot];
        sb[row * 128 + pos + 1] = p2[slot];
    }
    __syncthreads();
    if (tid < 64) {
        float t1 = -INFINITY, t2 = -INFINITY, t3 = -INFINITY, t4 = -INFINITY;
        for (int p = 0; p < 128; ++p) {
            const float v = sb[tid * 128 + ((p + tid) & 127)];   // rotated: 2-way banks
            if (v > t1)      { t4 = t3; t3 = t2; t2 = t1; t1 = v; }
            else if (v > t2) { t4 = t3; t3 = t2; t2 = v; }
            else if (v > t3) { t4 = t3; t3 = v; }
            else if (v > t4) { t4 = v; }
        }
        int* kc = kcand + (size_t)(rowblk + tid) * 8 + nhalf * 4;
        kc[0] = (int)(__float_as_uint(t1) & 8191u);
        kc[1] = (int)(__float_as_uint(t2) & 8191u);
        kc[2] = (int)(__float_as_uint(t3) & 8191u);
        kc[3] = (int)(__float_as_uint(t4) & 8191u);
    }
}

// ---------------- Phase B: exact fp32 recheck of 8 candidates + gather ----------------
// Arithmetic bit-replicates rounds 1/2 (which passed with absmax 0).
#define XTS 260   // padded row stride (floats): 4*rl mod 32 spreads banks uniformly
__global__ __launch_bounds__(256) void vq_phaseB8(
    const float* __restrict__ x, const float* __restrict__ embed,
    const int* __restrict__ kcand, float* __restrict__ out)
{
    __shared__ __align__(16) float xt[64 * XTS];   // ~66.5 KB
    __shared__ float rd[256];
    __shared__ int rk[256];
    __shared__ int win[64];
    const int tid = threadIdx.x;
    const int row0 = blockIdx.x * 64;

    // stage x tile, coalesced float4
    {
        const float4* src = (const float4*)(x + (size_t)row0 * DIM);
        float4* dst = (float4*)xt;
        for (int i = 0; i < 16; ++i) {
            const int idx = i * 256 + tid;
            dst[(idx >> 6) * (XTS / 4) + (idx & 63)] = src[idx];
        }
    }
    __syncthreads();

    const int rl = tid & 63;
    const int sub = tid >> 6;
    const int rg = row0 + rl;
    const float4* x4 = (const float4*)(xt + rl * XTS);

    // x_sq: 4 chunks of 64 sequential fmaf, ((c0+c1)+c2)+c3 — round-1 sequence
    float cs[4];
#pragma unroll
    for (int co = 0; co < 4; ++co) {
        float s = 0.f;
        for (int c4 = 0; c4 < 16; ++c4) {
            float4 v = x4[co * 16 + c4];
            s = fmaf(v.x, v.x, s); s = fmaf(v.y, v.y, s);
            s = fmaf(v.z, v.z, s); s = fmaf(v.w, v.w, s);
        }
        cs[co] = s;
    }
    const float xsq = ((cs[0] + cs[1]) + cs[2]) + cs[3];

    float bd = INFINITY; int bk = 0x7fffffff;
#pragma unroll
    for (int ci = 0; ci < 2; ++ci) {
        const int k = kcand[(size_t)rg * 8 + sub * 2 + ci];
        const float4* e4 = (const float4*)(embed + (size_t)k * DIM);
        float dot = 0.f, es = 0.f;
        for (int c4 = 0; c4 < 64; ++c4) {
            float4 xv = x4[c4], ev = e4[c4];
            dot = fmaf(xv.x, ev.x, dot); dot = fmaf(xv.y, ev.y, dot);
            dot = fmaf(xv.z, ev.z, dot); dot = fmaf(xv.w, ev.w, dot);
            es = fmaf(ev.x, ev.x, es); es = fmaf(ev.y, ev.y, es);
            es = fmaf(ev.z, ev.z, es); es = fmaf(ev.w, ev.w, es);
        }
        const float d = fmaf(-2.0f, dot, xsq) + es;   // round-1 rounding sequence
        if (d < bd || (d == bd && k < bk)) { bd = d; bk = k; }
    }
    rd[rl * 4 + sub] = bd;
    rk[rl * 4 + sub] = bk;
    __syncthreads();
    if (tid < 64) {
        float best = rd[tid * 4]; int bidx = rk[tid * 4];
#pragma unroll
        for (int t = 1; t < 4; ++t) {
            const float d2 = rd[tid * 4 + t]; const int k2 = rk[tid * 4 + t];
            if (d2 < best || (d2 == best && k2 < bidx)) { best = d2; bidx = k2; }
        }
        win[tid] = bidx;
    }
    __syncthreads();

    // coalesced gather
    {
        const float4* e4 = (const float4*)embed;
        float4* o4 = (float4*)out;
#pragma unroll
        for (int p = 0; p < 16; ++p) {
            const int r = (tid >> 6) + p * 4;
            const int k = win[r];
            o4[(size_t)(row0 + r) * 64 + (tid & 63)] = e4[(size_t)k * 64 + (tid & 63)];
        }
    }
}

// ---------------- Fallback (round-1 kernel, passed absmax 0) ----------------
#define BM 64
#define BN 128
#define BC 64
#define NKT (KCODES / BN)
#define NCC (DIM / BC)

__global__ __launch_bounds__(256, 3) void vq_argmin_gather(
    const float* __restrict__ x, const float* __restrict__ embed,
    float* __restrict__ out)
{
    __shared__ __align__(16) float xs[BC * BM];
    __shared__ __align__(16) float es[BC * BN];
    const int tid = threadIdx.x;
    const int tx = tid & 15;
    const int ty = tid >> 4;
    const int row0 = blockIdx.x * BM;
    float xsq[4];
    {
        const int m = tid >> 2;
        const int quarter = tid & 3;
        const float* xr = x + (size_t)(row0 + m) * DIM + quarter * 64;
        float s = 0.f;
        for (int c = 0; c < 64; ++c) s = fmaf(xr[c], xr[c], s);
        es[tid] = s;
        __syncthreads();
#pragma unroll
        for (int i = 0; i < 4; ++i) {
            const int r = 4 * ty + i;
            xsq[i] = ((es[4*r] + es[4*r+1]) + es[4*r+2]) + es[4*r+3];
        }
        __syncthreads();
    }
    float bd[4] = {INFINITY, INFINITY, INFINITY, INFINITY};
    int bk[4] = {0, 0, 0, 0};
    for (int kt = 0; kt < NKT; ++kt) {
        const int k0 = kt * BN;
        float acc[4][8];
#pragma unroll
        for (int i = 0; i < 4; ++i)
#pragma unroll
            for (int j = 0; j < 8; ++j) acc[i][j] = 0.f;
        float e_acc = 0.f;
        for (int cc = 0; cc < NCC; ++cc) {
            __syncthreads();
            {
                const int q = tid & 15;
                const int nb = tid >> 4;
#pragma unroll
                for (int p = 0; p < 4; ++p) {
                    const int m = nb + 16 * p;
                    const float4 v = *(const float4*)(x + (size_t)(row0 + m) * DIM + cc * BC + 4 * q);
                    xs[(4*q+0)*BM+m] = v.x; xs[(4*q+1)*BM+m] = v.y;
                    xs[(4*q+2)*BM+m] = v.z; xs[(4*q+3)*BM+m] = v.w;
                }
#pragma unroll
                for (int p = 0; p < 8; ++p) {
                    const int n = nb + 16 * p;
                    const float4 v = *(const float4*)(embed + (size_t)(k0 + n) * DIM + cc * BC + 4 * q);
                    es[(4*q+0)*BN+n] = v.x; es[(4*q+1)*BN+n] = v.y;
                    es[(4*q+2)*BN+n] = v.z; es[(4*q+3)*BN+n] = v.w;
                }
            }
            __syncthreads();
            if (tid < BN) {
#pragma unroll 8
                for (int c = 0; c < BC; ++c) { const float v = es[c*BN+tid]; e_acc = fmaf(v, v, e_acc); }
            }
#pragma unroll 8
            for (int c = 0; c < BC; ++c) {
                const float4 a0 = *(const float4*)&xs[c*BM+4*ty];
                const float4 b0 = *(const float4*)&es[c*BN+4*tx];
                const float4 b1 = *(const float4*)&es[c*BN+64+4*tx];
                const float a[4] = {a0.x, a0.y, a0.z, a0.w};
                const float b[8] = {b0.x, b0.y, b0.z, b0.w, b1.x, b1.y, b1.z, b1.w};
#pragma unroll
                for (int i = 0; i < 4; ++i)
#pragma unroll
                    for (int j = 0; j < 8; ++j) acc[i][j] = fmaf(a[i], b[j], acc[i][j]);
            }
        }
        __syncthreads();
        if (tid < BN) es[tid] = e_acc;
        __syncthreads();
        float esq[8];
#pragma unroll
        for (int j = 0; j < 4; ++j) { esq[j] = es[4*tx+j]; esq[4+j] = es[64+4*tx+j]; }
#pragma unroll
        for (int i = 0; i < 4; ++i)
#pragma unroll
            for (int j = 0; j < 8; ++j) {
                const float d = fmaf(-2.0f, acc[i][j], xsq[i]) + esq[j];
                const int kk = k0 + ((j < 4) ? (4*tx+j) : (64+4*tx+(j-4)));
                if (d < bd[i]) { bd[i] = d; bk[i] = kk; }
            }
    }
    __syncthreads();
    float* red_d = xs;
    int* red_k = (int*)es;
#pragma unroll
    for (int i = 0; i < 4; ++i) { const int r = 4*ty+i; red_d[r*16+tx] = bd[i]; red_k[r*16+tx] = bk[i]; }
    __syncthreads();
    int winner = 0;
    if (tid < BM) {
        float best = red_d[tid*16]; int bidx = red_k[tid*16];
#pragma unroll
        for (int t = 1; t < 16; ++t) {
            const float d2 = red_d[tid*16+t]; const int k2 = red_k[tid*16+t];
            if (d2 < best || (d2 == best && k2 < bidx)) { best = d2; bidx = k2; }
        }
        winner = bidx;
    }
    __syncthreads();
    int* wn = (int*)xs;
    if (tid < BM) wn[tid] = winner;
    __syncthreads();
    {
        const int q = tid & 63;
        const int rb = tid >> 6;
        const float4* e4 = (const float4*)embed;
        float4* o4 = (float4*)out;
#pragma unroll
        for (int p = 0; p < 16; ++p) {
            const int rr = rb + 4 * p;
            const int k = wn[rr];
            o4[(size_t)(row0 + rr) * 64 + q] = e4[(size_t)k * 64 + q];
        }
    }
}

extern "C" void kernel_launch(void* const* d_in, const int* in_sizes, int n_in,
                              void* d_out, int out_size, void* d_ws, size_t ws_size,
                              hipStream_t stream) {
    const float* x = (const float*)d_in[0];
    const float* embed = (const float*)d_in[1];
    float* out = (float*)d_out;

    if (ws_size < (size_t)WS_NEED) {
        hipLaunchKernelGGL(vq_argmin_gather, dim3(NROWS / BM), dim3(256), 0, stream, x, embed, out);
        return;
    }
    char* ws = (char*)d_ws;
    _Float16* Es = (_Float16*)(ws + ES_OFF);
    float* esq = (float*)(ws + ESQ_OFF);
    int* kcand = (int*)(ws + KC_OFF);

    hipLaunchKernelGGL(cvt_f16, dim3(2048), dim3(256), 0, stream, embed, Es, 524288);
    hipLaunchKernelGGL(compute_esq, dim3(32), dim3(256), 0, stream, embed, esq);
    hipLaunchKernelGGL(vq_phaseA_f16, dim3(512, 2), dim3(256), 0, stream, x, Es, esq, kcand);
    hipLaunchKernelGGL(vq_phaseB8, dim3(512), dim3(256), 0, stream, x, embed, kcand, out);
}

// Round 4
// 295.361 us; speedup vs baseline: 10.6322x; 1.1715x over previous
//
#include <hip/hip_runtime.h>
#include <math.h>

// EuclideanCodebook: x (8,4096,256) fp32, embed (8192,256) fp32
// out = embed[argmin_k ||x - e_k||^2], first-index tie rule.
//
// R4: single fused kernel. 128 rows/block x full 8192 codes, fp16 MFMA
// approximate scores (score = dot_f16(x,e) - 0.5*e_sq), double-buffered
// 64-code B tiles via swizzled global_load_lds (prefetch overlaps compute),
// packed (score|index) top-2 per 128-code stream -> per-row top-4 ->
// exact fp32 recheck (bit-replicates the validated R1-R3 arithmetic) ->
// coalesced gather. Plus one small cvt+esq prep kernel.

#define DIM 256
#define KCODES 8192
#define NROWS 32768
#define TILE_CODES 64
#define NT (KCODES / TILE_CODES)   // 128

typedef _Float16 half8 __attribute__((ext_vector_type(8)));
typedef _Float16 half4_t __attribute__((ext_vector_type(4)));
typedef float f32x4 __attribute__((ext_vector_type(4)));

// ---- ws layout (bytes) ----
#define ES_OFF 0u                 // 8192*256 f16 = 4194304
#define ESQ_OFF 4194304u          // 8192 f32     = 32768
#define WS_NEED 4227072u

#define GLOAD_LDS16(gp, lp) \
    __builtin_amdgcn_global_load_lds((const __attribute__((address_space(1))) void*)(gp), \
                                     (__attribute__((address_space(3))) void*)(lp), 16, 0, 0)

// ---------------- prep: embed fp32 -> fp16 + e_sq (approx use only) ----------------
// thread = (code, quarter): 32768 threads. Per-thread 64 contiguous floats.
__global__ void cvt_esq(const float* __restrict__ emb, _Float16* __restrict__ Es,
                        float* __restrict__ esq) {
    const int gid = blockIdx.x * 256 + threadIdx.x;
    const int code = gid >> 2, q = gid & 3;
    const float4* src = (const float4*)(emb + (size_t)code * DIM + q * 64);
    half4_t* dst = (half4_t*)(Es + (size_t)code * DIM + q * 64);
    float s = 0.f;
#pragma unroll
    for (int i = 0; i < 16; ++i) {
        const float4 v = src[i];
        half4_t h;
        h[0] = (_Float16)v.x; h[1] = (_Float16)v.y; h[2] = (_Float16)v.z; h[3] = (_Float16)v.w;
        dst[i] = h;
        s = fmaf(v.x, v.x, s); s = fmaf(v.y, v.y, s);
        s = fmaf(v.z, v.z, s); s = fmaf(v.w, v.w, s);
    }
    s += __shfl_xor(s, 1);
    s += __shfl_xor(s, 2);
    if (q == 0) esq[code] = s;
}

// ---------------- fused: MFMA score + top-4 + exact recheck + gather ----------------
// grid 256 blocks x 512 threads (8 waves). Block owns rows [blockIdx*128, +128).
// Wave wv: rg=wv&1 (row half), cg=wv>>1 (16-col slice of each 64-code tile).
__global__ __launch_bounds__(512, 2) void vq_fused(
    const float* __restrict__ x, const _Float16* __restrict__ Es,
    const float* __restrict__ esq, const float* __restrict__ embed,
    float* __restrict__ out)
{
    __shared__ __align__(16) _Float16 Bs[2][TILE_CODES * 256];  // 2 x 32 KB
    __shared__ float top4s[128][4];
    __shared__ float rd[128][4];
    __shared__ int rk[128][4];
    __shared__ int win[128];

    const int tid = threadIdx.x;
    const int lane = tid & 63;
    const int wv = tid >> 6;        // 0..7
    const int rg = wv & 1;          // row group
    const int cg = wv >> 1;         // col group 0..3
    const int lm = lane & 15;
    const int quad = lane >> 4;
    const int rowblk = blockIdx.x * 128;

    // ---- A fragments register-resident (fp32 x -> fp16), rows rg*64..+63 ----
    half8 af[4][8];
#pragma unroll
    for (int am = 0; am < 4; ++am) {
        const float* xr = x + (size_t)(rowblk + rg * 64 + am * 16 + lm) * DIM + quad * 8;
#pragma unroll
        for (int ks = 0; ks < 8; ++ks) {
            const float4 a = *(const float4*)(xr + ks * 32);
            const float4 b = *(const float4*)(xr + ks * 32 + 4);
            half8 h;
            h[0] = (_Float16)a.x; h[1] = (_Float16)a.y; h[2] = (_Float16)a.z; h[3] = (_Float16)a.w;
            h[4] = (_Float16)b.x; h[5] = (_Float16)b.y; h[6] = (_Float16)b.z; h[7] = (_Float16)b.w;
            af[am][ks] = h;
        }
    }

    // packed (score | index in low 13 mantissa bits) top-2 per row-slot.
    float p1[16], p2[16];
#pragma unroll
    for (int i = 0; i < 16; ++i) { p1[i] = -INFINITY; p2[i] = -INFINITY; }

    // staging role: wave stages codes [wv*8, wv*8+8) of each tile (4 x 1KB chunks)
    const int cl_lo = wv * 8 + (lane >> 5);   // +2*i per chunk
    const int bpos = lane & 31;               // 16B-block within a 512B code row

    // prologue: stage tile 0 into buf 0
#pragma unroll
    for (int i = 0; i < 4; ++i) {
        const int cl = cl_lo + 2 * i;
        const _Float16* g = Es + (size_t)cl * 256 + (size_t)((bpos ^ (cl & 7)) * 8);
        GLOAD_LDS16(g, &Bs[0][(wv * 8 + 2 * i) * 256]);
    }
    float e_nxt = esq[cg * 16 + lm];
    __syncthreads();   // drains staging vmcnt

    for (int nt = 0; nt < NT; ++nt) {
        const int cur = nt & 1;
        // prefetch next tile into the other buffer (issued before compute)
        if (nt + 1 < NT) {
#pragma unroll
            for (int i = 0; i < 4; ++i) {
                const int cl = (nt + 1) * TILE_CODES + cl_lo + 2 * i;
                const _Float16* g = Es + (size_t)cl * 256 + (size_t)((bpos ^ (cl & 7)) * 8);
                GLOAD_LDS16(g, &Bs[cur ^ 1][(wv * 8 + 2 * i) * 256]);
            }
        }
        const float e_cur = e_nxt;
        if (nt + 1 < NT) e_nxt = esq[(nt + 1) * TILE_CODES + cg * 16 + lm];

        // compute: acc[am] starts at -0.5*e_sq[col]; col = lm fixed per lane
        const float ev = -0.5f * e_cur;
        f32x4 acc[4];
#pragma unroll
        for (int am = 0; am < 4; ++am) { acc[am][0] = ev; acc[am][1] = ev; acc[am][2] = ev; acc[am][3] = ev; }
#pragma unroll
        for (int ks = 0; ks < 8; ++ks) {
            const half8 bf = *(const half8*)(&Bs[cur][(cg * 16 + lm) * 256 + ((ks * 4 + quad) ^ (lm & 7)) * 8]);
#pragma unroll
            for (int am = 0; am < 4; ++am)
                acc[am] = __builtin_amdgcn_mfma_f32_16x16x32_f16(af[am][ks], bf, acc[am], 0, 0, 0);
        }

        // epilogue: pack + branchless top-2 (4 ops/value, 16 values)
        const unsigned kk = (unsigned)(nt * TILE_CODES + cg * 16 + lm);
#pragma unroll
        for (int am = 0; am < 4; ++am)
#pragma unroll
            for (int r = 0; r < 4; ++r) {
                const float pv = __uint_as_float((__float_as_uint(acc[am][r]) & 0xFFFFE000u) | kk);
                const int s = am * 4 + r;
                p2[s] = fmaxf(p2[s], fminf(p1[s], pv));
                p1[s] = fmaxf(p1[s], pv);
            }

        __syncthreads();   // (a) all reads of Bs[cur^1] from prev iter done
                           // (b) compiler drains vmcnt -> prefetch visible
    }

    // ---- merge: per row 128 streams x top-2 -> top-4 ----
    float* mb = (float*)Bs;   // [128][128] packed values, 64 KB (reuses tile buffers)
#pragma unroll
    for (int s = 0; s < 16; ++s) {
        const int row = rg * 64 + (s >> 2) * 16 + quad * 4 + (s & 3);
        const int pos = cg * 32 + lm * 2;
        mb[row * 128 + pos] = p1[s];
        mb[row * 128 + pos + 1] = p2[s];
    }
    __syncthreads();
    if (tid < 128) {
        float t1 = -INFINITY, t2 = -INFINITY, t3 = -INFINITY, t4 = -INFINITY;
        for (int p = 0; p < 128; ++p) {
            const float v = mb[tid * 128 + ((p + tid) & 127)];   // rotated banks
            const float m1 = fminf(t1, v);
            t1 = fmaxf(t1, v);
            const float m2 = fminf(t2, m1);
            t2 = fmaxf(t2, m1);
            const float m3 = fminf(t3, m2);
            t3 = fmaxf(t3, m2);
            t4 = fmaxf(t4, m3);
        }
        top4s[tid][0] = t1; top4s[tid][1] = t2; top4s[tid][2] = t3; top4s[tid][3] = t4;
    }
    __syncthreads();

    // ---- exact fp32 recheck: 4 threads/row, 1 candidate each ----
    // Bit-replicates the validated R1-R3 arithmetic.
    {
        const int row = tid >> 2;
        const int ci = tid & 3;
        const int k = (int)(__float_as_uint(top4s[row][ci]) & 8191u);
        const float4* x4 = (const float4*)(x + (size_t)(rowblk + row) * DIM);
        float cs[4];
#pragma unroll
        for (int co = 0; co < 4; ++co) {
            float s = 0.f;
            for (int c4 = 0; c4 < 16; ++c4) {
                const float4 v = x4[co * 16 + c4];
                s = fmaf(v.x, v.x, s); s = fmaf(v.y, v.y, s);
                s = fmaf(v.z, v.z, s); s = fmaf(v.w, v.w, s);
            }
            cs[co] = s;
        }
        const float xsq = ((cs[0] + cs[1]) + cs[2]) + cs[3];
        const float4* e4 = (const float4*)(embed + (size_t)k * DIM);
        float dot = 0.f, es = 0.f;
        for (int c4 = 0; c4 < 64; ++c4) {
            const float4 xv = x4[c4], evv = e4[c4];
            dot = fmaf(xv.x, evv.x, dot); dot = fmaf(xv.y, evv.y, dot);
            dot = fmaf(xv.z, evv.z, dot); dot = fmaf(xv.w, evv.w, dot);
            es = fmaf(evv.x, evv.x, es); es = fmaf(evv.y, evv.y, es);
            es = fmaf(evv.z, evv.z, es); es = fmaf(evv.w, evv.w, es);
        }
        rd[row][ci] = fmaf(-2.0f, dot, xsq) + es;   // validated rounding sequence
        rk[row][ci] = k;
    }
    __syncthreads();
    if (tid < 128) {
        float best = rd[tid][0]; int bidx = rk[tid][0];
#pragma unroll
        for (int t = 1; t < 4; ++t) {
            const float d2 = rd[tid][t]; const int k2 = rk[tid][t];
            if (d2 < best || (d2 == best && k2 < bidx)) { best = d2; bidx = k2; }
        }
        win[tid] = bidx;
    }
    __syncthreads();

    // ---- coalesced gather ----
    {
        const int q = tid & 63;
        const int rb = tid >> 6;
        const float4* e4 = (const float4*)embed;
        float4* o4 = (float4*)out;
#pragma unroll
        for (int p = 0; p < 16; ++p) {
            const int r = rb + p * 8;
            const int k = win[r];
            o4[(size_t)(rowblk + r) * 64 + q] = e4[(size_t)k * 64 + q];
        }
    }
}

// ---------------- Fallback (round-1 kernel, passed absmax 0) ----------------
#define BM 64
#define BN 128
#define BC 64
#define NKT (KCODES / BN)
#define NCC (DIM / BC)

__global__ __launch_bounds__(256, 3) void vq_argmin_gather(
    const float* __restrict__ x, const float* __restrict__ embed,
    float* __restrict__ out)
{
    __shared__ __align__(16) float xs[BC * BM];
    __shared__ __align__(16) float es[BC * BN];
    const int tid = threadIdx.x;
    const int tx = tid & 15;
    const int ty = tid >> 4;
    const int row0 = blockIdx.x * BM;
    float xsq[4];
    {
        const int m = tid >> 2;
        const int quarter = tid & 3;
        const float* xr = x + (size_t)(row0 + m) * DIM + quarter * 64;
        float s = 0.f;
        for (int c = 0; c < 64; ++c) s = fmaf(xr[c], xr[c], s);
        es[tid] = s;
        __syncthreads();
#pragma unroll
        for (int i = 0; i < 4; ++i) {
            const int r = 4 * ty + i;
            xsq[i] = ((es[4*r] + es[4*r+1]) + es[4*r+2]) + es[4*r+3];
        }
        __syncthreads();
    }
    float bd[4] = {INFINITY, INFINITY, INFINITY, INFINITY};
    int bk[4] = {0, 0, 0, 0};
    for (int kt = 0; kt < NKT; ++kt) {
        const int k0 = kt * BN;
        float acc[4][8];
#pragma unroll
        for (int i = 0; i < 4; ++i)
#pragma unroll
            for (int j = 0; j < 8; ++j) acc[i][j] = 0.f;
        float e_acc = 0.f;
        for (int cc = 0; cc < NCC; ++cc) {
            __syncthreads();
            {
                const int q = tid & 15;
                const int nb = tid >> 4;
#pragma unroll
                for (int p = 0; p < 4; ++p) {
                    const int m = nb + 16 * p;
                    const float4 v = *(const float4*)(x + (size_t)(row0 + m) * DIM + cc * BC + 4 * q);
                    xs[(4*q+0)*BM+m] = v.x; xs[(4*q+1)*BM+m] = v.y;
                    xs[(4*q+2)*BM+m] = v.z; xs[(4*q+3)*BM+m] = v.w;
                }
#pragma unroll
                for (int p = 0; p < 8; ++p) {
                    const int n = nb + 16 * p;
                    const float4 v = *(const float4*)(embed + (size_t)(k0 + n) * DIM + cc * BC + 4 * q);
                    es[(4*q+0)*BN+n] = v.x; es[(4*q+1)*BN+n] = v.y;
                    es[(4*q+2)*BN+n] = v.z; es[(4*q+3)*BN+n] = v.w;
                }
            }
            __syncthreads();
            if (tid < BN) {
#pragma unroll 8
                for (int c = 0; c < BC; ++c) { const float v = es[c*BN+tid]; e_acc = fmaf(v, v, e_acc); }
            }
#pragma unroll 8
            for (int c = 0; c < BC; ++c) {
                const float4 a0 = *(const float4*)&xs[c*BM+4*ty];
                const float4 b0 = *(const float4*)&es[c*BN+4*tx];
                const float4 b1 = *(const float4*)&es[c*BN+64+4*tx];
                const float a[4] = {a0.x, a0.y, a0.z, a0.w};
                const float b[8] = {b0.x, b0.y, b0.z, b0.w, b1.x, b1.y, b1.z, b1.w};
#pragma unroll
                for (int i = 0; i < 4; ++i)
#pragma unroll
                    for (int j = 0; j < 8; ++j) acc[i][j] = fmaf(a[i], b[j], acc[i][j]);
            }
        }
        __syncthreads();
        if (tid < BN) es[tid] = e_acc;
        __syncthreads();
        float esq2[8];
#pragma unroll
        for (int j = 0; j < 4; ++j) { esq2[j] = es[4*tx+j]; esq2[4+j] = es[64+4*tx+j]; }
#pragma unroll
        for (int i = 0; i < 4; ++i)
#pragma unroll
            for (int j = 0; j < 8; ++j) {
                const float d = fmaf(-2.0f, acc[i][j], xsq[i]) + esq2[j];
                const int kk = k0 + ((j < 4) ? (4*tx+j) : (64+4*tx+(j-4)));
                if (d < bd[i]) { bd[i] = d; bk[i] = kk; }
            }
    }
    __syncthreads();
    float* red_d = xs;
    int* red_k = (int*)es;
#pragma unroll
    for (int i = 0; i < 4; ++i) { const int r = 4*ty+i; red_d[r*16+tx] = bd[i]; red_k[r*16+tx] = bk[i]; }
    __syncthreads();
    int winner = 0;
    if (tid < BM) {
        float best = red_d[tid*16]; int bidx = red_k[tid*16];
#pragma unroll
        for (int t = 1; t < 16; ++t) {
            const float d2 = red_d[tid*16+t]; const int k2 = red_k[tid*16+t];
            if (d2 < best || (d2 == best && k2 < bidx)) { best = d2; bidx = k2; }
        }
        winner = bidx;
    }
    __syncthreads();
    int* wn = (int*)xs;
    if (tid < BM) wn[tid] = winner;
    __syncthreads();
    {
        const int q = tid & 63;
        const int rb = tid >> 6;
        const float4* e4 = (const float4*)embed;
        float4* o4 = (float4*)out;
#pragma unroll
        for (int p = 0; p < 16; ++p) {
            const int rr = rb + 4 * p;
            const int k = wn[rr];
            o4[(size_t)(row0 + rr) * 64 + q] = e4[(size_t)k * 64 + q];
        }
    }
}

extern "C" void kernel_launch(void* const* d_in, const int* in_sizes, int n_in,
                              void* d_out, int out_size, void* d_ws, size_t ws_size,
                              hipStream_t stream) {
    const float* x = (const float*)d_in[0];
    const float* embed = (const float*)d_in[1];
    float* out = (float*)d_out;

    if (ws_size < (size_t)WS_NEED) {
        hipLaunchKernelGGL(vq_argmin_gather, dim3(NROWS / BM), dim3(256), 0, stream, x, embed, out);
        return;
    }
    char* ws = (char*)d_ws;
    _Float16* Es = (_Float16*)(ws + ES_OFF);
    float* esq = (float*)(ws + ESQ_OFF);

    hipLaunchKernelGGL(cvt_esq, dim3(128), dim3(256), 0, stream, embed, Es, esq);
    hipLaunchKernelGGL(vq_fused, dim3(256), dim3(512), 0, stream, x, Es, esq, embed, out);
}

// Round 5
// 294.617 us; speedup vs baseline: 10.6591x; 1.0025x over previous
//
#include <hip/hip_runtime.h>
#include <math.h>

// EuclideanCodebook: x (8,4096,256) fp32, embed (8192,256) fp32
// out = embed[argmin_k ||x - e_k||^2], first-index tie rule.
//
// R5: R4 fused structure, but waves own 32 rows x 32 cols (4 row-groups x
// 2 col-groups) so A-fragments are 64 VGPRs, not 128 -> no scratch spill
// (R4's WRITE_SIZE showed ~29 MB of spill traffic). Everything else kept:
// fp16 MFMA approx scores, double-buffered 64-code B tiles via swizzled
// global_load_lds, packed (score|idx) top-2 -> top-4 -> exact fp32 recheck
// (bit-replicates validated R1-R4 arithmetic) -> coalesced gather.

#define DIM 256
#define KCODES 8192
#define NROWS 32768
#define TILE_CODES 64
#define NT (KCODES / TILE_CODES)   // 128

typedef _Float16 half8 __attribute__((ext_vector_type(8)));
typedef _Float16 half4_t __attribute__((ext_vector_type(4)));
typedef float f32x4 __attribute__((ext_vector_type(4)));

// ---- ws layout (bytes) ----
#define ES_OFF 0u                 // 8192*256 f16 = 4194304
#define ESQ_OFF 4194304u          // 8192 f32     = 32768
#define WS_NEED 4227072u

#define GLOAD_LDS16(gp, lp) \
    __builtin_amdgcn_global_load_lds((const __attribute__((address_space(1))) void*)(gp), \
                                     (__attribute__((address_space(3))) void*)(lp), 16, 0, 0)

// ---------------- prep: embed fp32 -> fp16 + e_sq (approx use only) ----------------
__global__ void cvt_esq(const float* __restrict__ emb, _Float16* __restrict__ Es,
                        float* __restrict__ esq) {
    const int gid = blockIdx.x * 256 + threadIdx.x;
    const int code = gid >> 2, q = gid & 3;
    const float4* src = (const float4*)(emb + (size_t)code * DIM + q * 64);
    half4_t* dst = (half4_t*)(Es + (size_t)code * DIM + q * 64);
    float s = 0.f;
#pragma unroll
    for (int i = 0; i < 16; ++i) {
        const float4 v = src[i];
        half4_t h;
        h[0] = (_Float16)v.x; h[1] = (_Float16)v.y; h[2] = (_Float16)v.z; h[3] = (_Float16)v.w;
        dst[i] = h;
        s = fmaf(v.x, v.x, s); s = fmaf(v.y, v.y, s);
        s = fmaf(v.z, v.z, s); s = fmaf(v.w, v.w, s);
    }
    s += __shfl_xor(s, 1);
    s += __shfl_xor(s, 2);
    if (q == 0) esq[code] = s;
}

// ---------------- fused: MFMA score + top-4 + exact recheck + gather ----------------
// grid 256 blocks x 512 threads (8 waves). Block owns rows [blockIdx*128, +128).
// Wave wv: rowg = wv&3 (32-row slice), colg = wv>>2 (32-col slice of 64-code tile).
__global__ __launch_bounds__(512, 2) void vq_fused(
    const float* __restrict__ x, const _Float16* __restrict__ Es,
    const float* __restrict__ esq, const float* __restrict__ embed,
    float* __restrict__ out)
{
    __shared__ __align__(16) _Float16 Bs[2][TILE_CODES * 256];  // 2 x 32 KB
    __shared__ float top4s[128][4];
    __shared__ float rd[128][4];
    __shared__ int rk[128][4];
    __shared__ int win[128];

    const int tid = threadIdx.x;
    const int lane = tid & 63;
    const int wv = tid >> 6;        // 0..7
    const int rowg = wv & 3;        // 4 row groups x 32 rows
    const int colg = wv >> 2;       // 2 col groups x 32 cols
    const int lm = lane & 15;
    const int quad = lane >> 4;
    const int rowblk = blockIdx.x * 128;

    // ---- A fragments register-resident (fp32 x -> fp16): 32 rows -> 64 VGPRs ----
    half8 af[2][8];
#pragma unroll
    for (int am = 0; am < 2; ++am) {
        const float* xr = x + (size_t)(rowblk + rowg * 32 + am * 16 + lm) * DIM + quad * 8;
#pragma unroll
        for (int ks = 0; ks < 8; ++ks) {
            const float4 a = *(const float4*)(xr + ks * 32);
            const float4 b = *(const float4*)(xr + ks * 32 + 4);
            half8 h;
            h[0] = (_Float16)a.x; h[1] = (_Float16)a.y; h[2] = (_Float16)a.z; h[3] = (_Float16)a.w;
            h[4] = (_Float16)b.x; h[5] = (_Float16)b.y; h[6] = (_Float16)b.z; h[7] = (_Float16)b.w;
            af[am][ks] = h;
        }
    }

    // packed (score | index in low 13 mantissa bits) top-2 per row-slot
    // (8 slots = 2 am x 4 acc-regs; 2 bn column streams folded into each slot).
    float p1[8], p2[8];
#pragma unroll
    for (int i = 0; i < 8; ++i) { p1[i] = -INFINITY; p2[i] = -INFINITY; }

    // staging role: wave stages codes [wv*8, wv*8+8) of each tile (4 x 1KB chunks)
    const int cl_lo = wv * 8 + (lane >> 5);
    const int bpos = lane & 31;

    // prologue: stage tile 0 into buf 0
#pragma unroll
    for (int i = 0; i < 4; ++i) {
        const int cl = cl_lo + 2 * i;
        const _Float16* g = Es + (size_t)cl * 256 + (size_t)((bpos ^ (cl & 7)) * 8);
        GLOAD_LDS16(g, &Bs[0][(wv * 8 + 2 * i) * 256]);
    }
    float e_nxt0 = esq[colg * 32 + lm];
    float e_nxt1 = esq[colg * 32 + 16 + lm];
    __syncthreads();

    for (int nt = 0; nt < NT; ++nt) {
        const int cur = nt & 1;
        if (nt + 1 < NT) {
#pragma unroll
            for (int i = 0; i < 4; ++i) {
                const int cl = (nt + 1) * TILE_CODES + cl_lo + 2 * i;
                const _Float16* g = Es + (size_t)cl * 256 + (size_t)((bpos ^ (cl & 7)) * 8);
                GLOAD_LDS16(g, &Bs[cur ^ 1][(wv * 8 + 2 * i) * 256]);
            }
        }
        const float e0 = e_nxt0, e1 = e_nxt1;
        if (nt + 1 < NT) {
            e_nxt0 = esq[(nt + 1) * TILE_CODES + colg * 32 + lm];
            e_nxt1 = esq[(nt + 1) * TILE_CODES + colg * 32 + 16 + lm];
        }

        f32x4 acc[2][2];
        {
            const float v0 = -0.5f * e0, v1 = -0.5f * e1;
            const f32x4 i0 = {v0, v0, v0, v0};
            const f32x4 i1 = {v1, v1, v1, v1};
#pragma unroll
            for (int am = 0; am < 2; ++am) { acc[am][0] = i0; acc[am][1] = i1; }
        }
#pragma unroll
        for (int ks = 0; ks < 8; ++ks) {
            half8 bf[2];
#pragma unroll
            for (int bn = 0; bn < 2; ++bn) {
                const int cl = colg * 32 + bn * 16 + lm;
                bf[bn] = *(const half8*)(&Bs[cur][cl * 256 + ((ks * 4 + quad) ^ (lm & 7)) * 8]);
            }
#pragma unroll
            for (int am = 0; am < 2; ++am)
#pragma unroll
                for (int bn = 0; bn < 2; ++bn)
                    acc[am][bn] = __builtin_amdgcn_mfma_f32_16x16x32_f16(af[am][ks], bf[bn], acc[am][bn], 0, 0, 0);
        }

        // epilogue: pack + branchless top-2 (2 bn streams into 8 row-slots)
#pragma unroll
        for (int bn = 0; bn < 2; ++bn) {
            const unsigned kk = (unsigned)(nt * TILE_CODES + colg * 32 + bn * 16 + lm);
#pragma unroll
            for (int am = 0; am < 2; ++am)
#pragma unroll
                for (int r = 0; r < 4; ++r) {
                    const float pv = __uint_as_float((__float_as_uint(acc[am][bn][r]) & 0xFFFFE000u) | kk);
                    const int s = am * 4 + r;
                    p2[s] = fmaxf(p2[s], fminf(p1[s], pv));
                    p1[s] = fmaxf(p1[s], pv);
                }
        }

        __syncthreads();   // reads of Bs[cur^1] done + prefetch drained/visible
    }

    // ---- merge: per row, 64 streams x top-2 = 128 packed values -> top-4 ----
    float* mb = (float*)Bs;   // [128][128] floats, 64 KB (reuses tile buffers)
#pragma unroll
    for (int s = 0; s < 8; ++s) {
        const int row = rowg * 32 + (s >> 2) * 16 + quad * 4 + (s & 3);
        const int pos = colg * 64 + lm * 2;   // streams: colg x lm x {p1,p2} (+bn folded already)
        mb[row * 128 + pos] = p1[s];
        mb[row * 128 + pos + 1] = p2[s];
        // note: bn streams were folded into p1/p2, so only 32 lanes' worth per colg;
        // fill the other 32 slots with -inf duplicates to keep layout simple
        mb[row * 128 + colg * 64 + 32 + lm * 2] = -INFINITY;
        mb[row * 128 + colg * 64 + 32 + lm * 2 + 1] = -INFINITY;
    }
    __syncthreads();
    if (tid < 128) {
        float t1 = -INFINITY, t2 = -INFINITY, t3 = -INFINITY, t4 = -INFINITY;
        for (int p = 0; p < 128; ++p) {
            const float v = mb[tid * 128 + ((p + tid) & 127)];   // rotated banks
            const float m1 = fminf(t1, v);
            t1 = fmaxf(t1, v);
            const float m2 = fminf(t2, m1);
            t2 = fmaxf(t2, m1);
            const float m3 = fminf(t3, m2);
            t3 = fmaxf(t3, m2);
            t4 = fmaxf(t4, m3);
        }
        top4s[tid][0] = t1; top4s[tid][1] = t2; top4s[tid][2] = t3; top4s[tid][3] = t4;
    }
    __syncthreads();

    // ---- exact fp32 recheck: 4 threads/row, 1 candidate each ----
    {
        const int row = tid >> 2;
        const int ci = tid & 3;
        const int k = (int)(__float_as_uint(top4s[row][ci]) & 8191u);
        const float4* x4 = (const float4*)(x + (size_t)(rowblk + row) * DIM);
        float cs[4];
#pragma unroll
        for (int co = 0; co < 4; ++co) {
            float s = 0.f;
            for (int c4 = 0; c4 < 16; ++c4) {
                const float4 v = x4[co * 16 + c4];
                s = fmaf(v.x, v.x, s); s = fmaf(v.y, v.y, s);
                s = fmaf(v.z, v.z, s); s = fmaf(v.w, v.w, s);
            }
            cs[co] = s;
        }
        const float xsq = ((cs[0] + cs[1]) + cs[2]) + cs[3];
        const float4* e4 = (const float4*)(embed + (size_t)k * DIM);
        float dot = 0.f, es = 0.f;
        for (int c4 = 0; c4 < 64; ++c4) {
            const float4 xv = x4[c4], evv = e4[c4];
            dot = fmaf(xv.x, evv.x, dot); dot = fmaf(xv.y, evv.y, dot);
            dot = fmaf(xv.z, evv.z, dot); dot = fmaf(xv.w, evv.w, dot);
            es = fmaf(evv.x, evv.x, es); es = fmaf(evv.y, evv.y, es);
            es = fmaf(evv.z, evv.z, es); es = fmaf(evv.w, evv.w, es);
        }
        rd[row][ci] = fmaf(-2.0f, dot, xsq) + es;   // validated rounding sequence
        rk[row][ci] = k;
    }
    __syncthreads();
    if (tid < 128) {
        float best = rd[tid][0]; int bidx = rk[tid][0];
#pragma unroll
        for (int t = 1; t < 4; ++t) {
            const float d2 = rd[tid][t]; const int k2 = rk[tid][t];
            if (d2 < best || (d2 == best && k2 < bidx)) { best = d2; bidx = k2; }
        }
        win[tid] = bidx;
    }
    __syncthreads();

    // ---- coalesced gather ----
    {
        const int q = tid & 63;
        const int rb = tid >> 6;
        const float4* e4 = (const float4*)embed;
        float4* o4 = (float4*)out;
#pragma unroll
        for (int p = 0; p < 16; ++p) {
            const int r = rb + p * 8;
            const int k = win[r];
            o4[(size_t)(rowblk + r) * 64 + q] = e4[(size_t)k * 64 + q];
        }
    }
}

// ---------------- Fallback (round-1 kernel, passed absmax 0) ----------------
#define BM 64
#define BN 128
#define BC 64
#define NKT (KCODES / BN)
#define NCC (DIM / BC)

__global__ __launch_bounds__(256, 3) void vq_argmin_gather(
    const float* __restrict__ x, const float* __restrict__ embed,
    float* __restrict__ out)
{
    __shared__ __align__(16) float xs[BC * BM];
    __shared__ __align__(16) float es[BC * BN];
    const int tid = threadIdx.x;
    const int tx = tid & 15;
    const int ty = tid >> 4;
    const int row0 = blockIdx.x * BM;
    float xsq[4];
    {
        const int m = tid >> 2;
        const int quarter = tid & 3;
        const float* xr = x + (size_t)(row0 + m) * DIM + quarter * 64;
        float s = 0.f;
        for (int c = 0; c < 64; ++c) s = fmaf(xr[c], xr[c], s);
        es[tid] = s;
        __syncthreads();
#pragma unroll
        for (int i = 0; i < 4; ++i) {
            const int r = 4 * ty + i;
            xsq[i] = ((es[4*r] + es[4*r+1]) + es[4*r+2]) + es[4*r+3];
        }
        __syncthreads();
    }
    float bd[4] = {INFINITY, INFINITY, INFINITY, INFINITY};
    int bk[4] = {0, 0, 0, 0};
    for (int kt = 0; kt < NKT; ++kt) {
        const int k0 = kt * BN;
        float acc[4][8];
#pragma unroll
        for (int i = 0; i < 4; ++i)
#pragma unroll
            for (int j = 0; j < 8; ++j) acc[i][j] = 0.f;
        float e_acc = 0.f;
        for (int cc = 0; cc < NCC; ++cc) {
            __syncthreads();
            {
                const int q = tid & 15;
                const int nb = tid >> 4;
#pragma unroll
                for (int p = 0; p < 4; ++p) {
                    const int m = nb + 16 * p;
                    const float4 v = *(const float4*)(x + (size_t)(row0 + m) * DIM + cc * BC + 4 * q);
                    xs[(4*q+0)*BM+m] = v.x; xs[(4*q+1)*BM+m] = v.y;
                    xs[(4*q+2)*BM+m] = v.z; xs[(4*q+3)*BM+m] = v.w;
                }
#pragma unroll
                for (int p = 0; p < 8; ++p) {
                    const int n = nb + 16 * p;
                    const float4 v = *(const float4*)(embed + (size_t)(k0 + n) * DIM + cc * BC + 4 * q);
                    es[(4*q+0)*BN+n] = v.x; es[(4*q+1)*BN+n] = v.y;
                    es[(4*q+2)*BN+n] = v.z; es[(4*q+3)*BN+n] = v.w;
                }
            }
            __syncthreads();
            if (tid < BN) {
#pragma unroll 8
                for (int c = 0; c < BC; ++c) { const float v = es[c*BN+tid]; e_acc = fmaf(v, v, e_acc); }
            }
#pragma unroll 8
            for (int c = 0; c < BC; ++c) {
                const float4 a0 = *(const float4*)&xs[c*BM+4*ty];
                const float4 b0 = *(const float4*)&es[c*BN+4*tx];
                const float4 b1 = *(const float4*)&es[c*BN+64+4*tx];
                const float a[4] = {a0.x, a0.y, a0.z, a0.w};
                const float b[8] = {b0.x, b0.y, b0.z, b0.w, b1.x, b1.y, b1.z, b1.w};
#pragma unroll
                for (int i = 0; i < 4; ++i)
#pragma unroll
                    for (int j = 0; j < 8; ++j) acc[i][j] = fmaf(a[i], b[j], acc[i][j]);
            }
        }
        __syncthreads();
        if (tid < BN) es[tid] = e_acc;
        __syncthreads();
        float esq2[8];
#pragma unroll
        for (int j = 0; j < 4; ++j) { esq2[j] = es[4*tx+j]; esq2[4+j] = es[64+4*tx+j]; }
#pragma unroll
        for (int i = 0; i < 4; ++i)
#pragma unroll
            for (int j = 0; j < 8; ++j) {
                const float d = fmaf(-2.0f, acc[i][j], xsq[i]) + esq2[j];
                const int kk = k0 + ((j < 4) ? (4*tx+j) : (64+4*tx+(j-4)));
                if (d < bd[i]) { bd[i] = d; bk[i] = kk; }
            }
    }
    __syncthreads();
    float* red_d = xs;
    int* red_k = (int*)es;
#pragma unroll
    for (int i = 0; i < 4; ++i) { const int r = 4*ty+i; red_d[r*16+tx] = bd[i]; red_k[r*16+tx] = bk[i]; }
    __syncthreads();
    int winner = 0;
    if (tid < BM) {
        float best = red_d[tid*16]; int bidx = red_k[tid*16];
#pragma unroll
        for (int t = 1; t < 16; ++t) {
            const float d2 = red_d[tid*16+t]; const int k2 = red_k[tid*16+t];
            if (d2 < best || (d2 == best && k2 < bidx)) { best = d2; bidx = k2; }
        }
        winner = bidx;
    }
    __syncthreads();
    int* wn = (int*)xs;
    if (tid < BM) wn[tid] = winner;
    __syncthreads();
    {
        const int q = tid & 63;
        const int rb = tid >> 6;
        const float4* e4 = (const float4*)embed;
        float4* o4 = (float4*)out;
#pragma unroll
        for (int p = 0; p < 16; ++p) {
            const int rr = rb + 4 * p;
            const int k = wn[rr];
            o4[(size_t)(row0 + rr) * 64 + q] = e4[(size_t)k * 64 + q];
        }
    }
}

extern "C" void kernel_launch(void* const* d_in, const int* in_sizes, int n_in,
                              void* d_out, int out_size, void* d_ws, size_t ws_size,
                              hipStream_t stream) {
    const float* x = (const float*)d_in[0];
    const float* embed = (const float*)d_in[1];
    float* out = (float*)d_out;

    if (ws_size < (size_t)WS_NEED) {
        hipLaunchKernelGGL(vq_argmin_gather, dim3(NROWS / BM), dim3(256), 0, stream, x, embed, out);
        return;
    }
    char* ws = (char*)d_ws;
    _Float16* Es = (_Float16*)(ws + ES_OFF);
    float* esq = (float*)(ws + ESQ_OFF);

    hipLaunchKernelGGL(cvt_esq, dim3(128), dim3(256), 0, stream, embed, Es, esq);
    hipLaunchKernelGGL(vq_fused, dim3(256), dim3(512), 0, stream, x, Es, esq, embed, out);
}

// Round 6
// 290.017 us; speedup vs baseline: 10.8281x; 1.0159x over previous
//
#include <hip/hip_runtime.h>
#include <math.h>

// EuclideanCodebook: x (8,4096,256) fp32, embed (8192,256) fp32
// out = embed[argmin_k ||x - e_k||^2], first-index tie rule.
//
// R6: R5 structure, but occupancy pinned with amdgpu_waves_per_eu(1,2) so the
// register allocator gets a 256-VGPR budget (R4/R5: backend heuristic forced a
// 128-VGPR / 4-waves-per-EU target and spilled ~49 regs -> 26 MB scratch
// writes + 40 MB reloads per dispatch). Demand ~130 regs -> no spill.
// Also: merge buffer stride 65 (was 128/64) to kill reader bank conflicts.
// Everything else unchanged: fp16 MFMA approx scores, double-buffered 64-code
// B tiles via swizzled global_load_lds, packed (score|idx) top-2 -> top-4 ->
// exact fp32 recheck (bit-replicates validated R1-R5 arithmetic) -> gather.

#define DIM 256
#define KCODES 8192
#define NROWS 32768
#define TILE_CODES 64
#define NT (KCODES / TILE_CODES)   // 128

typedef _Float16 half8 __attribute__((ext_vector_type(8)));
typedef _Float16 half4_t __attribute__((ext_vector_type(4)));
typedef float f32x4 __attribute__((ext_vector_type(4)));

// ---- ws layout (bytes) ----
#define ES_OFF 0u                 // 8192*256 f16 = 4194304
#define ESQ_OFF 4194304u          // 8192 f32     = 32768
#define WS_NEED 4227072u

#define GLOAD_LDS16(gp, lp) \
    __builtin_amdgcn_global_load_lds((const __attribute__((address_space(1))) void*)(gp), \
                                     (__attribute__((address_space(3))) void*)(lp), 16, 0, 0)

// ---------------- prep: embed fp32 -> fp16 + e_sq (approx use only) ----------------
__global__ void cvt_esq(const float* __restrict__ emb, _Float16* __restrict__ Es,
                        float* __restrict__ esq) {
    const int gid = blockIdx.x * 256 + threadIdx.x;
    const int code = gid >> 2, q = gid & 3;
    const float4* src = (const float4*)(emb + (size_t)code * DIM + q * 64);
    half4_t* dst = (half4_t*)(Es + (size_t)code * DIM + q * 64);
    float s = 0.f;
#pragma unroll
    for (int i = 0; i < 16; ++i) {
        const float4 v = src[i];
        half4_t h;
        h[0] = (_Float16)v.x; h[1] = (_Float16)v.y; h[2] = (_Float16)v.z; h[3] = (_Float16)v.w;
        dst[i] = h;
        s = fmaf(v.x, v.x, s); s = fmaf(v.y, v.y, s);
        s = fmaf(v.z, v.z, s); s = fmaf(v.w, v.w, s);
    }
    s += __shfl_xor(s, 1);
    s += __shfl_xor(s, 2);
    if (q == 0) esq[code] = s;
}

// ---------------- fused: MFMA score + top-4 + exact recheck + gather ----------------
// grid 256 blocks x 512 threads (8 waves). Block owns rows [blockIdx*128, +128).
// Wave wv: rowg = wv&3 (32-row slice), colg = wv>>2 (32-col slice of 64-code tile).
// waves_per_eu(1,2): 2 waves/SIMD max -> 256-VGPR budget -> no spill (demand ~130).
__global__ __attribute__((amdgpu_flat_work_group_size(512, 512)))
__attribute__((amdgpu_waves_per_eu(1, 2))) void vq_fused(
    const float* __restrict__ x, const _Float16* __restrict__ Es,
    const float* __restrict__ esq, const float* __restrict__ embed,
    float* __restrict__ out)
{
    __shared__ __align__(16) _Float16 Bs[2][TILE_CODES * 256];  // 2 x 32 KB
    __shared__ float top4s[128][4];
    __shared__ float rd[128][4];
    __shared__ int rk[128][4];
    __shared__ int win[128];

    const int tid = threadIdx.x;
    const int lane = tid & 63;
    const int wv = tid >> 6;        // 0..7
    const int rowg = wv & 3;        // 4 row groups x 32 rows
    const int colg = wv >> 2;       // 2 col groups x 32 cols
    const int lm = lane & 15;
    const int quad = lane >> 4;
    const int rowblk = blockIdx.x * 128;

    // ---- A fragments register-resident (fp32 x -> fp16): 32 rows -> 64 VGPRs ----
    half8 af[2][8];
#pragma unroll
    for (int am = 0; am < 2; ++am) {
        const float* xr = x + (size_t)(rowblk + rowg * 32 + am * 16 + lm) * DIM + quad * 8;
#pragma unroll
        for (int ks = 0; ks < 8; ++ks) {
            const float4 a = *(const float4*)(xr + ks * 32);
            const float4 b = *(const float4*)(xr + ks * 32 + 4);
            half8 h;
            h[0] = (_Float16)a.x; h[1] = (_Float16)a.y; h[2] = (_Float16)a.z; h[3] = (_Float16)a.w;
            h[4] = (_Float16)b.x; h[5] = (_Float16)b.y; h[6] = (_Float16)b.z; h[7] = (_Float16)b.w;
            af[am][ks] = h;
        }
    }

    // packed (score | index in low 13 mantissa bits) top-2 per row-slot
    // (8 slots = 2 am x 4 acc-regs; 2 bn column streams folded into each slot).
    float p1[8], p2[8];
#pragma unroll
    for (int i = 0; i < 8; ++i) { p1[i] = -INFINITY; p2[i] = -INFINITY; }

    // staging role: wave stages codes [wv*8, wv*8+8) of each tile (4 x 1KB chunks)
    const int cl_lo = wv * 8 + (lane >> 5);
    const int bpos = lane & 31;

    // prologue: stage tile 0 into buf 0
#pragma unroll
    for (int i = 0; i < 4; ++i) {
        const int cl = cl_lo + 2 * i;
        const _Float16* g = Es + (size_t)cl * 256 + (size_t)((bpos ^ (cl & 7)) * 8);
        GLOAD_LDS16(g, &Bs[0][(wv * 8 + 2 * i) * 256]);
    }
    float e_nxt0 = esq[colg * 32 + lm];
    float e_nxt1 = esq[colg * 32 + 16 + lm];
    __syncthreads();

    for (int nt = 0; nt < NT; ++nt) {
        const int cur = nt & 1;
        if (nt + 1 < NT) {
#pragma unroll
            for (int i = 0; i < 4; ++i) {
                const int cl = (nt + 1) * TILE_CODES + cl_lo + 2 * i;
                const _Float16* g = Es + (size_t)cl * 256 + (size_t)((bpos ^ (cl & 7)) * 8);
                GLOAD_LDS16(g, &Bs[cur ^ 1][(wv * 8 + 2 * i) * 256]);
            }
        }
        const float e0 = e_nxt0, e1 = e_nxt1;
        if (nt + 1 < NT) {
            e_nxt0 = esq[(nt + 1) * TILE_CODES + colg * 32 + lm];
            e_nxt1 = esq[(nt + 1) * TILE_CODES + colg * 32 + 16 + lm];
        }

        f32x4 acc[2][2];
        {
            const float v0 = -0.5f * e0, v1 = -0.5f * e1;
            const f32x4 i0 = {v0, v0, v0, v0};
            const f32x4 i1 = {v1, v1, v1, v1};
#pragma unroll
            for (int am = 0; am < 2; ++am) { acc[am][0] = i0; acc[am][1] = i1; }
        }
#pragma unroll
        for (int ks = 0; ks < 8; ++ks) {
            half8 bf[2];
#pragma unroll
            for (int bn = 0; bn < 2; ++bn) {
                const int cl = colg * 32 + bn * 16 + lm;
                bf[bn] = *(const half8*)(&Bs[cur][cl * 256 + ((ks * 4 + quad) ^ (lm & 7)) * 8]);
            }
#pragma unroll
            for (int am = 0; am < 2; ++am)
#pragma unroll
                for (int bn = 0; bn < 2; ++bn)
                    acc[am][bn] = __builtin_amdgcn_mfma_f32_16x16x32_f16(af[am][ks], bf[bn], acc[am][bn], 0, 0, 0);
        }

        // epilogue: pack + branchless top-2 (2 bn streams into 8 row-slots)
#pragma unroll
        for (int bn = 0; bn < 2; ++bn) {
            const unsigned kk = (unsigned)(nt * TILE_CODES + colg * 32 + bn * 16 + lm);
#pragma unroll
            for (int am = 0; am < 2; ++am)
#pragma unroll
                for (int r = 0; r < 4; ++r) {
                    const float pv = __uint_as_float((__float_as_uint(acc[am][bn][r]) & 0xFFFFE000u) | kk);
                    const int s = am * 4 + r;
                    p2[s] = fmaxf(p2[s], fminf(p1[s], pv));
                    p1[s] = fmaxf(p1[s], pv);
                }
        }

        __syncthreads();   // reads of Bs[cur^1] done + prefetch drained/visible
    }

    // ---- merge: per row, 32 streams x top-2 = 64 packed values -> top-4 ----
    // stride 65 floats: reader banks = (tid*65+p)%32 = (tid+p)%32 -> conflict-free
    float* mb = (float*)Bs;   // [128][65] floats = 33.3 KB (reuses tile buffers)
#pragma unroll
    for (int s = 0; s < 8; ++s) {
        const int row = rowg * 32 + (s >> 2) * 16 + quad * 4 + (s & 3);
        const int pos = (colg * 16 + lm) * 2;
        mb[row * 65 + pos] = p1[s];
        mb[row * 65 + pos + 1] = p2[s];
    }
    __syncthreads();
    if (tid < 128) {
        float t1 = -INFINITY, t2 = -INFINITY, t3 = -INFINITY, t4 = -INFINITY;
        for (int p = 0; p < 64; ++p) {
            const float v = mb[tid * 65 + p];
            const float m1 = fminf(t1, v);
            t1 = fmaxf(t1, v);
            const float m2 = fminf(t2, m1);
            t2 = fmaxf(t2, m1);
            const float m3 = fminf(t3, m2);
            t3 = fmaxf(t3, m2);
            t4 = fmaxf(t4, m3);
        }
        top4s[tid][0] = t1; top4s[tid][1] = t2; top4s[tid][2] = t3; top4s[tid][3] = t4;
    }
    __syncthreads();

    // ---- exact fp32 recheck: 4 threads/row, 1 candidate each ----
    {
        const int row = tid >> 2;
        const int ci = tid & 3;
        const int k = (int)(__float_as_uint(top4s[row][ci]) & 8191u);
        const float4* x4 = (const float4*)(x + (size_t)(rowblk + row) * DIM);
        float cs[4];
#pragma unroll
        for (int co = 0; co < 4; ++co) {
            float s = 0.f;
            for (int c4 = 0; c4 < 16; ++c4) {
                const float4 v = x4[co * 16 + c4];
                s = fmaf(v.x, v.x, s); s = fmaf(v.y, v.y, s);
                s = fmaf(v.z, v.z, s); s = fmaf(v.w, v.w, s);
            }
            cs[co] = s;
        }
        const float xsq = ((cs[0] + cs[1]) + cs[2]) + cs[3];
        const float4* e4 = (const float4*)(embed + (size_t)k * DIM);
        float dot = 0.f, es = 0.f;
        for (int c4 = 0; c4 < 64; ++c4) {
            const float4 xv = x4[c4], evv = e4[c4];
            dot = fmaf(xv.x, evv.x, dot); dot = fmaf(xv.y, evv.y, dot);
            dot = fmaf(xv.z, evv.z, dot); dot = fmaf(xv.w, evv.w, dot);
            es = fmaf(evv.x, evv.x, es); es = fmaf(evv.y, evv.y, es);
            es = fmaf(evv.z, evv.z, es); es = fmaf(evv.w, evv.w, es);
        }
        rd[row][ci] = fmaf(-2.0f, dot, xsq) + es;   // validated rounding sequence
        rk[row][ci] = k;
    }
    __syncthreads();
    if (tid < 128) {
        float best = rd[tid][0]; int bidx = rk[tid][0];
#pragma unroll
        for (int t = 1; t < 4; ++t) {
            const float d2 = rd[tid][t]; const int k2 = rk[tid][t];
            if (d2 < best || (d2 == best && k2 < bidx)) { best = d2; bidx = k2; }
        }
        win[tid] = bidx;
    }
    __syncthreads();

    // ---- coalesced gather ----
    {
        const int q = tid & 63;
        const int rb = tid >> 6;
        const float4* e4 = (const float4*)embed;
        float4* o4 = (float4*)out;
#pragma unroll
        for (int p = 0; p < 16; ++p) {
            const int r = rb + p * 8;
            const int k = win[r];
            o4[(size_t)(rowblk + r) * 64 + q] = e4[(size_t)k * 64 + q];
        }
    }
}

// ---------------- Fallback (round-1 kernel, passed absmax 0) ----------------
#define BM 64
#define BN 128
#define BC 64
#define NKT (KCODES / BN)
#define NCC (DIM / BC)

__global__ __launch_bounds__(256, 3) void vq_argmin_gather(
    const float* __restrict__ x, const float* __restrict__ embed,
    float* __restrict__ out)
{
    __shared__ __align__(16) float xs[BC * BM];
    __shared__ __align__(16) float es[BC * BN];
    const int tid = threadIdx.x;
    const int tx = tid & 15;
    const int ty = tid >> 4;
    const int row0 = blockIdx.x * BM;
    float xsq[4];
    {
        const int m = tid >> 2;
        const int quarter = tid & 3;
        const float* xr = x + (size_t)(row0 + m) * DIM + quarter * 64;
        float s = 0.f;
        for (int c = 0; c < 64; ++c) s = fmaf(xr[c], xr[c], s);
        es[tid] = s;
        __syncthreads();
#pragma unroll
        for (int i = 0; i < 4; ++i) {
            const int r = 4 * ty + i;
            xsq[i] = ((es[4*r] + es[4*r+1]) + es[4*r+2]) + es[4*r+3];
        }
        __syncthreads();
    }
    float bd[4] = {INFINITY, INFINITY, INFINITY, INFINITY};
    int bk[4] = {0, 0, 0, 0};
    for (int kt = 0; kt < NKT; ++kt) {
        const int k0 = kt * BN;
        float acc[4][8];
#pragma unroll
        for (int i = 0; i < 4; ++i)
#pragma unroll
            for (int j = 0; j < 8; ++j) acc[i][j] = 0.f;
        float e_acc = 0.f;
        for (int cc = 0; cc < NCC; ++cc) {
            __syncthreads();
            {
                const int q = tid & 15;
                const int nb = tid >> 4;
#pragma unroll
                for (int p = 0; p < 4; ++p) {
                    const int m = nb + 16 * p;
                    const float4 v = *(const float4*)(x + (size_t)(row0 + m) * DIM + cc * BC + 4 * q);
                    xs[(4*q+0)*BM+m] = v.x; xs[(4*q+1)*BM+m] = v.y;
                    xs[(4*q+2)*BM+m] = v.z; xs[(4*q+3)*BM+m] = v.w;
                }
#pragma unroll
                for (int p = 0; p < 8; ++p) {
                    const int n = nb + 16 * p;
                    const float4 v = *(const float4*)(embed + (size_t)(k0 + n) * DIM + cc * BC + 4 * q);
                    es[(4*q+0)*BN+n] = v.x; es[(4*q+1)*BN+n] = v.y;
                    es[(4*q+2)*BN+n] = v.z; es[(4*q+3)*BN+n] = v.w;
                }
            }
            __syncthreads();
            if (tid < BN) {
#pragma unroll 8
                for (int c = 0; c < BC; ++c) { const float v = es[c*BN+tid]; e_acc = fmaf(v, v, e_acc); }
            }
#pragma unroll 8
            for (int c = 0; c < BC; ++c) {
                const float4 a0 = *(const float4*)&xs[c*BM+4*ty];
                const float4 b0 = *(const float4*)&es[c*BN+4*tx];
                const float4 b1 = *(const float4*)&es[c*BN+64+4*tx];
                const float a[4] = {a0.x, a0.y, a0.z, a0.w};
                const float b[8] = {b0.x, b0.y, b0.z, b0.w, b1.x, b1.y, b1.z, b1.w};
#pragma unroll
                for (int i = 0; i < 4; ++i)
#pragma unroll
                    for (int j = 0; j < 8; ++j) acc[i][j] = fmaf(a[i], b[j], acc[i][j]);
            }
        }
        __syncthreads();
        if (tid < BN) es[tid] = e_acc;
        __syncthreads();
        float esq2[8];
#pragma unroll
        for (int j = 0; j < 4; ++j) { esq2[j] = es[4*tx+j]; esq2[4+j] = es[64+4*tx+j]; }
#pragma unroll
        for (int i = 0; i < 4; ++i)
#pragma unroll
            for (int j = 0; j < 8; ++j) {
                const float d = fmaf(-2.0f, acc[i][j], xsq[i]) + esq2[j];
                const int kk = k0 + ((j < 4) ? (4*tx+j) : (64+4*tx+(j-4)));
                if (d < bd[i]) { bd[i] = d; bk[i] = kk; }
            }
    }
    __syncthreads();
    float* red_d = xs;
    int* red_k = (int*)es;
#pragma unroll
    for (int i = 0; i < 4; ++i) { const int r = 4*ty+i; red_d[r*16+tx] = bd[i]; red_k[r*16+tx] = bk[i]; }
    __syncthreads();
    int winner = 0;
    if (tid < BM) {
        float best = red_d[tid*16]; int bidx = red_k[tid*16];
#pragma unroll
        for (int t = 1; t < 16; ++t) {
            const float d2 = red_d[tid*16+t]; const int k2 = red_k[tid*16+t];
            if (d2 < best || (d2 == best && k2 < bidx)) { best = d2; bidx = k2; }
        }
        winner = bidx;
    }
    __syncthreads();
    int* wn = (int*)xs;
    if (tid < BM) wn[tid] = winner;
    __syncthreads();
    {
        const int q = tid & 63;
        const int rb = tid >> 6;
        const float4* e4 = (const float4*)embed;
        float4* o4 = (float4*)out;
#pragma unroll
        for (int p = 0; p < 16; ++p) {
            const int rr = rb + 4 * p;
            const int k = wn[rr];
            o4[(size_t)(row0 + rr) * 64 + q] = e4[(size_t)k * 64 + q];
        }
    }
}

extern "C" void kernel_launch(void* const* d_in, const int* in_sizes, int n_in,
                              void* d_out, int out_size, void* d_ws, size_t ws_size,
                              hipStream_t stream) {
    const float* x = (const float*)d_in[0];
    const float* embed = (const float*)d_in[1];
    float* out = (float*)d_out;

    if (ws_size < (size_t)WS_NEED) {
        hipLaunchKernelGGL(vq_argmin_gather, dim3(NROWS / BM), dim3(256), 0, stream, x, embed, out);
        return;
    }
    char* ws = (char*)d_ws;
    _Float16* Es = (_Float16*)(ws + ES_OFF);
    float* esq = (float*)(ws + ESQ_OFF);

    hipLaunchKernelGGL(cvt_esq, dim3(128), dim3(256), 0, stream, embed, Es, esq);
    hipLaunchKernelGGL(vq_fused, dim3(256), dim3(512), 0, stream, x, Es, esq, embed, out);
}